// Round 6
// baseline (460.106 us; speedup 1.0000x reference)
//
#include <hip/hip_runtime.h>
#include <stdint.h>

// ---------------------------------------------------------------------------
// GPT-2 block, runtime dtype-adaptive (fp32 or bf16 external), bf16 internal,
// fp32 accumulate. MI355X / gfx950.
// R6: BK=64 K-loop (4x 8KB LDS half-buffers, halved barrier count) for all
// MFMA GEMMs; attention unpaired to 1024 blocks (4/CU) with longest-first
// dispatch order.
// ---------------------------------------------------------------------------

typedef __attribute__((ext_vector_type(8))) short bf16x8;
typedef __attribute__((ext_vector_type(8))) unsigned short u16x8;
typedef __attribute__((ext_vector_type(4))) float f32x4;

#define NEG_BIG -30000.0f
#define EXP2SC 0.18033688011112042f   // 0.125 * log2(e)

__device__ __forceinline__ float b2f(unsigned short u) {
  union { unsigned int i; float f; } c; c.i = ((unsigned int)u) << 16; return c.f;
}
__device__ __forceinline__ unsigned short f2b(float f) {
  union { float f; unsigned int u; } c; c.f = f;
  unsigned int r = c.u + 0x7fffu + ((c.u >> 16) & 1u);   // RNE
  return (unsigned short)(r >> 16);
}
__device__ __forceinline__ float ldx(const void* p, size_t i, int f32) {
  return f32 ? ((const float*)p)[i] : b2f(((const unsigned short*)p)[i]);
}
__device__ __forceinline__ void gld_lds16(const void* g, void* l) {
  __builtin_amdgcn_global_load_lds(
      (__attribute__((address_space(1))) void*)(void*)g,
      (__attribute__((address_space(3))) void*)l, 16, 0, 0);
}

// ---------------------------------------------------------------------------
__global__ void detect_k(const unsigned short* __restrict__ x, int* __restrict__ flag) {
  int lane = threadIdx.x;
  int cnt = 0;
#pragma unroll
  for (int j = 0; j < 4; ++j) {
    unsigned e = (x[lane * 4 + j] >> 7) & 0xFF;
    if (e >= 100 && e <= 145) cnt++;
  }
#pragma unroll
  for (int off = 32; off; off >>= 1) cnt += __shfl_down(cnt, off);
  if (lane == 0) *flag = (cnt < 220) ? 1 : 0;
}

// ---------------------------------------------------------------------------
// 64x64 tile transpose, adaptive input, bf16 out: out[n*K+k] = in[k*N+n]
// ---------------------------------------------------------------------------
__global__ __launch_bounds__(256) void transpose_k(
    const void* __restrict__ in, unsigned short* __restrict__ out,
    int K, int N, const int* __restrict__ flag) {
  int fm = *flag;
  __shared__ unsigned short tile[64][72];
  int n0 = blockIdx.x * 64, k0 = blockIdx.y * 64;
  int t = threadIdx.x;
  int r = t >> 3, c0 = (t & 7) * 8;
  if (fm) {
    const float* inf = (const float*)in;
#pragma unroll
    for (int p = 0; p < 2; ++p) {
      int k = r + p * 32;
      float4 v0 = *(const float4*)(inf + (size_t)(k0 + k) * N + n0 + c0);
      float4 v1 = *(const float4*)(inf + (size_t)(k0 + k) * N + n0 + c0 + 4);
      tile[k][c0 + 0] = f2b(v0.x); tile[k][c0 + 1] = f2b(v0.y);
      tile[k][c0 + 2] = f2b(v0.z); tile[k][c0 + 3] = f2b(v0.w);
      tile[k][c0 + 4] = f2b(v1.x); tile[k][c0 + 5] = f2b(v1.y);
      tile[k][c0 + 6] = f2b(v1.z); tile[k][c0 + 7] = f2b(v1.w);
    }
  } else {
    const unsigned short* inu = (const unsigned short*)in;
#pragma unroll
    for (int p = 0; p < 2; ++p) {
      int k = r + p * 32;
      u16x8 v = *(const u16x8*)(inu + (size_t)(k0 + k) * N + n0 + c0);
      *(u16x8*)&tile[k][c0] = v;
    }
  }
  __syncthreads();
#pragma unroll
  for (int p = 0; p < 2; ++p) {
    int n = r + p * 32;
    u16x8 v;
#pragma unroll
    for (int j = 0; j < 8; ++j) v[j] = tile[c0 + j][n];
    *(u16x8*)(out + (size_t)(n0 + n) * K + k0 + c0) = v;
  }
}

// ---------------------------------------------------------------------------
// LayerNorm D=1024
// ---------------------------------------------------------------------------
__global__ __launch_bounds__(256) void ln_k(
    const void* __restrict__ x, const void* __restrict__ sc,
    const void* __restrict__ bs, unsigned short* __restrict__ out,
    const int* __restrict__ flag, int xAdap) {
  int fm = *flag;
  int fx = xAdap ? fm : 0;
  int row = blockIdx.x, t = threadIdx.x;
  float f0, f1, f2, f3;
  if (fx) {
    float4 xv = ((const float4*)x)[(size_t)row * 256 + t];
    f0 = xv.x; f1 = xv.y; f2 = xv.z; f3 = xv.w;
  } else {
    ushort4 xv = ((const ushort4*)x)[(size_t)row * 256 + t];
    f0 = b2f(xv.x); f1 = b2f(xv.y); f2 = b2f(xv.z); f3 = b2f(xv.w);
  }
  float s = f0 + f1 + f2 + f3;
  float q = f0 * f0 + f1 * f1 + f2 * f2 + f3 * f3;
#pragma unroll
  for (int off = 32; off; off >>= 1) {
    s += __shfl_down(s, off);
    q += __shfl_down(q, off);
  }
  __shared__ float red[8];
  int w = t >> 6, lane = t & 63;
  if (lane == 0) { red[w] = s; red[w + 4] = q; }
  __syncthreads();
  float S = red[0] + red[1] + red[2] + red[3];
  float Q = red[4] + red[5] + red[6] + red[7];
  float mean = S * (1.f / 1024.f);
  float var = Q * (1.f / 1024.f) - mean * mean;
  float rstd = rsqrtf(var + 1e-5f);
  int c = t * 4;
  ushort4 o;
  o.x = f2b((f0 - mean) * rstd * ldx(sc, c, fm)     + ldx(bs, c, fm));
  o.y = f2b((f1 - mean) * rstd * ldx(sc, c + 1, fm) + ldx(bs, c + 1, fm));
  o.z = f2b((f2 - mean) * rstd * ldx(sc, c + 2, fm) + ldx(bs, c + 2, fm));
  o.w = f2b((f3 - mean) * rstd * ldx(sc, c + 3, fm) + ldx(bs, c + 3, fm));
  ((ushort4*)(out + (size_t)row * 1024))[t] = o;
}

// ---------------------------------------------------------------------------
// GEMM: C[M,N] = A[M,K]*Bt[N,K]^T + bias; EPI: 0=none 1=gelu 2=+res
// 128x128 tile, BK=64 via two 32-col half-buffers per operand (64B-stride
// fragment rows stay 2-way/free in LDS banks). K % 64 == 0.
// ---------------------------------------------------------------------------
template <int EPI>
__global__ __launch_bounds__(256) void gemm_bt(
    const unsigned short* __restrict__ A, const unsigned short* __restrict__ Bt,
    const void* __restrict__ bias, const void* __restrict__ res,
    void* __restrict__ C, int M, int N, int K,
    const int* __restrict__ flag, int resAdap, int outAdap) {
  int fm = *flag;
  int fr = resAdap ? fm : 0;
  int fo = outAdap ? fm : 0;
  __shared__ unsigned short As[2][128 * 32];
  __shared__ unsigned short Bs[2][128 * 32];
  int t = threadIdx.x;
  int bn = blockIdx.x * 128, bm = blockIdx.y * 128;
  int w = t >> 6, lane = t & 63, quad = lane >> 4, l16 = lane & 15;
  int wm = (w >> 1) * 64, wn = (w & 1) * 64;
  f32x4 acc[4][4] = {};

  int c1 = t, c2 = t + 256;
  int r1 = c1 >> 2, e1 = (c1 & 3) * 8;
  int r2 = c2 >> 2, e2 = (c2 & 3) * 8;
  const unsigned short* a1 = A + (size_t)(bm + r1) * K + e1;
  const unsigned short* a2 = A + (size_t)(bm + r2) * K + e2;
  const unsigned short* b1 = Bt + (size_t)(bn + r1) * K + e1;
  const unsigned short* b2 = Bt + (size_t)(bn + r2) * K + e2;

  for (int k0 = 0; k0 < K; k0 += 64) {
    gld_lds16(a1 + k0,      As[0] + c1 * 8);
    gld_lds16(a2 + k0,      As[0] + c2 * 8);
    gld_lds16(a1 + k0 + 32, As[1] + c1 * 8);
    gld_lds16(a2 + k0 + 32, As[1] + c2 * 8);
    gld_lds16(b1 + k0,      Bs[0] + c1 * 8);
    gld_lds16(b2 + k0,      Bs[0] + c2 * 8);
    gld_lds16(b1 + k0 + 32, Bs[1] + c1 * 8);
    gld_lds16(b2 + k0 + 32, Bs[1] + c2 * 8);
    __syncthreads();
#pragma unroll
    for (int h = 0; h < 2; ++h) {
      bf16x8 af[4], bfr[4];
#pragma unroll
      for (int i = 0; i < 4; ++i)
        af[i] = *(const bf16x8*)&As[h][(wm + i * 16 + l16) * 32 + quad * 8];
#pragma unroll
      for (int j = 0; j < 4; ++j)
        bfr[j] = *(const bf16x8*)&Bs[h][(wn + j * 16 + l16) * 32 + quad * 8];
#pragma unroll
      for (int i = 0; i < 4; ++i)
#pragma unroll
        for (int j = 0; j < 4; ++j)
          acc[i][j] = __builtin_amdgcn_mfma_f32_16x16x32_bf16(af[i], bfr[j], acc[i][j], 0, 0, 0);
    }
    __syncthreads();
  }

#pragma unroll
  for (int j = 0; j < 4; ++j) {
    int col = bn + wn + j * 16 + l16;
    float bb = ldx(bias, col, fm);
#pragma unroll
    for (int i = 0; i < 4; ++i) {
      int row0 = bm + wm + i * 16 + quad * 4;
#pragma unroll
      for (int r = 0; r < 4; ++r) {
        float v = acc[i][j][r] + bb;
        if (EPI == 1) {
          float u = 0.7978845608f * (v + 0.044715f * v * v * v);
          float e = __expf(2.f * u);          // tanh(u) = 1 - 2/(e^{2u}+1)
          float th = 1.f - 2.f / (e + 1.f);
          v = 0.5f * v * (1.f + th);
        } else if (EPI == 2) {
          v += ldx(res, (size_t)(row0 + r) * N + col, fr);
        }
        size_t idx = (size_t)(row0 + r) * N + col;
        if (fo) ((float*)C)[idx] = v;
        else    ((unsigned short*)C)[idx] = f2b(v);
      }
    }
  }
}

// ---------------------------------------------------------------------------
// Split-K GEMM: P[z][M,N] = A[:, z*Kh:(z+1)*Kh] * Bt^T (fp32, no epilogue)
// BK=64 structure identical to gemm_bt. Kh % 64 == 0.
// ---------------------------------------------------------------------------
__global__ __launch_bounds__(256) void gemm_pk(
    const unsigned short* __restrict__ A, const unsigned short* __restrict__ Bt,
    float* __restrict__ P, int M, int N, int Kh, int Kfull) {
  __shared__ unsigned short As[2][128 * 32];
  __shared__ unsigned short Bs[2][128 * 32];
  int t = threadIdx.x;
  int bn = blockIdx.x * 128, bm = blockIdx.y * 128;
  int koff = blockIdx.z * Kh;
  float* Pz = P + (size_t)blockIdx.z * M * N;
  int w = t >> 6, lane = t & 63, quad = lane >> 4, l16 = lane & 15;
  int wm = (w >> 1) * 64, wn = (w & 1) * 64;
  f32x4 acc[4][4] = {};

  int c1 = t, c2 = t + 256;
  int r1 = c1 >> 2, e1 = (c1 & 3) * 8;
  int r2 = c2 >> 2, e2 = (c2 & 3) * 8;
  const unsigned short* a1 = A + (size_t)(bm + r1) * Kfull + koff + e1;
  const unsigned short* a2 = A + (size_t)(bm + r2) * Kfull + koff + e2;
  const unsigned short* b1 = Bt + (size_t)(bn + r1) * Kfull + koff + e1;
  const unsigned short* b2 = Bt + (size_t)(bn + r2) * Kfull + koff + e2;

  for (int k0 = 0; k0 < Kh; k0 += 64) {
    gld_lds16(a1 + k0,      As[0] + c1 * 8);
    gld_lds16(a2 + k0,      As[0] + c2 * 8);
    gld_lds16(a1 + k0 + 32, As[1] + c1 * 8);
    gld_lds16(a2 + k0 + 32, As[1] + c2 * 8);
    gld_lds16(b1 + k0,      Bs[0] + c1 * 8);
    gld_lds16(b2 + k0,      Bs[0] + c2 * 8);
    gld_lds16(b1 + k0 + 32, Bs[1] + c1 * 8);
    gld_lds16(b2 + k0 + 32, Bs[1] + c2 * 8);
    __syncthreads();
#pragma unroll
    for (int h = 0; h < 2; ++h) {
      bf16x8 af[4], bfr[4];
#pragma unroll
      for (int i = 0; i < 4; ++i)
        af[i] = *(const bf16x8*)&As[h][(wm + i * 16 + l16) * 32 + quad * 8];
#pragma unroll
      for (int j = 0; j < 4; ++j)
        bfr[j] = *(const bf16x8*)&Bs[h][(wn + j * 16 + l16) * 32 + quad * 8];
#pragma unroll
      for (int i = 0; i < 4; ++i)
#pragma unroll
        for (int j = 0; j < 4; ++j)
          acc[i][j] = __builtin_amdgcn_mfma_f32_16x16x32_bf16(af[i], bfr[j], acc[i][j], 0, 0, 0);
    }
    __syncthreads();
  }

#pragma unroll
  for (int j = 0; j < 4; ++j) {
    int col = bn + wn + j * 16 + l16;
#pragma unroll
    for (int i = 0; i < 4; ++i) {
      int row0 = bm + wm + i * 16 + quad * 4;
#pragma unroll
      for (int r = 0; r < 4; ++r)
        Pz[(size_t)(row0 + r) * N + col] = acc[i][j][r];
    }
  }
}

// ---------------------------------------------------------------------------
// reduce: out = P0 + P1 + bias (+ res), N power of two
// ---------------------------------------------------------------------------
__global__ __launch_bounds__(256) void reduce2_k(
    const float* __restrict__ P0, const float* __restrict__ P1,
    const void* __restrict__ bias, const void* __restrict__ res,
    void* __restrict__ out, int N,
    const int* __restrict__ flag, int resAdap, int outAdap) {
  int fm = *flag;
  int fr = resAdap ? fm : 0;
  int fo = outAdap ? fm : 0;
  size_t idx = ((size_t)blockIdx.x * 256 + threadIdx.x) * 4;
  float4 p0 = *(const float4*)(P0 + idx);
  float4 p1 = *(const float4*)(P1 + idx);
  int col = (int)(idx & (size_t)(N - 1));
  float v0 = p0.x + p1.x + ldx(bias, col, fm)     + ldx(res, idx, fr);
  float v1 = p0.y + p1.y + ldx(bias, col + 1, fm) + ldx(res, idx + 1, fr);
  float v2 = p0.z + p1.z + ldx(bias, col + 2, fm) + ldx(res, idx + 2, fr);
  float v3 = p0.w + p1.w + ldx(bias, col + 3, fm) + ldx(res, idx + 3, fr);
  if (fo) {
    float4 o; o.x = v0; o.y = v1; o.z = v2; o.w = v3;
    *(float4*)((float*)out + idx) = o;
  } else {
    ushort4 o; o.x = f2b(v0); o.y = f2b(v1); o.z = f2b(v2); o.w = f2b(v3);
    *(ushort4*)((unsigned short*)out + idx) = o;
  }
}

// ---------------------------------------------------------------------------
// Flash attention, causal, S^T formulation. One 64-row q-tile per block.
// Grid (32, 32): qt = 31 - blockIdx.x so longest blocks dispatch first.
// ---------------------------------------------------------------------------
__global__ __launch_bounds__(256) void attn_k(
    const unsigned short* __restrict__ qkv, unsigned short* __restrict__ out) {
  __shared__ unsigned short Ks[64 * 72];
  __shared__ unsigned int   Vt[64 * 35];
  __shared__ unsigned short Ps[4 * 16 * 72];
  int t = threadIdx.x, w = t >> 6, lane = t & 63, quad = lane >> 4, l16 = lane & 15;
  int qt = 31 - blockIdx.x, bh = blockIdx.y, b = bh >> 4, h = bh & 15;
  const unsigned short* base = qkv + (size_t)b * 2048 * 3072 + h * 64;
  unsigned short* Pw = Ps + w * 16 * 72;
  int srow = t >> 3, d0 = (t & 7) * 8;

  int q0 = qt * 64;
  int qrel = w * 16 + l16;
  const unsigned short* qp = base + (size_t)(q0 + qrel) * 3072;
  bf16x8 bq0 = *(const bf16x8*)(qp + quad * 8);
  bf16x8 bq1 = *(const bf16x8*)(qp + 32 + quad * 8);
  float m_i = NEG_BIG, l_i = 0.f;
  f32x4 O[4] = {};

#pragma unroll 1
  for (int kt = 0; kt <= qt; ++kt) {
    const unsigned short* kb = base + (size_t)(kt * 64) * 3072;
    {
      u16x8 k0v = *(const u16x8*)(kb + (size_t)srow * 3072 + 1024 + d0);
      u16x8 k1v = *(const u16x8*)(kb + (size_t)(srow + 32) * 3072 + 1024 + d0);
      *(u16x8*)&Ks[srow * 72 + d0] = k0v;
      *(u16x8*)&Ks[(srow + 32) * 72 + d0] = k1v;
      int sp = t >> 3;
      u16x8 va = *(const u16x8*)(kb + (size_t)(2 * sp) * 3072 + 2048 + d0);
      u16x8 vb = *(const u16x8*)(kb + (size_t)(2 * sp + 1) * 3072 + 2048 + d0);
#pragma unroll
      for (int j = 0; j < 8; ++j)
        Vt[(d0 + j) * 35 + sp] = (unsigned int)va[j] | ((unsigned int)vb[j] << 16);
    }
    __syncthreads();

    f32x4 ST[4];
#pragma unroll
    for (int i = 0; i < 4; ++i) {
      bf16x8 ak0 = *(const bf16x8*)&Ks[(i * 16 + l16) * 72 + quad * 8];
      bf16x8 ak1 = *(const bf16x8*)&Ks[(i * 16 + l16) * 72 + 32 + quad * 8];
      f32x4 z = {};
      z = __builtin_amdgcn_mfma_f32_16x16x32_bf16(ak0, bq0, z, 0, 0, 0);
      ST[i] = __builtin_amdgcn_mfma_f32_16x16x32_bf16(ak1, bq1, z, 0, 0, 0);
    }

    bool dm = (kt == qt);
    float p[4][4];
    float mx = NEG_BIG;
#pragma unroll
    for (int i = 0; i < 4; ++i)
#pragma unroll
      for (int r = 0; r < 4; ++r) {
        float v = ST[i][r] * EXP2SC;
        int srel = i * 16 + quad * 4 + r;
        if (dm && srel > qrel) v = NEG_BIG;
        p[i][r] = v;
        mx = fmaxf(mx, v);
      }
    mx = fmaxf(mx, __shfl_xor(mx, 16));
    mx = fmaxf(mx, __shfl_xor(mx, 32));
    float mn = fmaxf(m_i, mx);
    float alpha = exp2f(m_i - mn);
    m_i = mn;
    float sum = 0.f;
#pragma unroll
    for (int i = 0; i < 4; ++i)
#pragma unroll
      for (int r = 0; r < 4; ++r) {
        float e = exp2f(p[i][r] - mn);
        p[i][r] = e;
        sum += e;
      }
    sum += __shfl_xor(sum, 16);
    sum += __shfl_xor(sum, 32);
    l_i = alpha * l_i + sum;

#pragma unroll
    for (int i = 0; i < 4; ++i) {
      uint2 pr;
      pr.x = (unsigned int)f2b(p[i][0]) | ((unsigned int)f2b(p[i][1]) << 16);
      pr.y = (unsigned int)f2b(p[i][2]) | ((unsigned int)f2b(p[i][3]) << 16);
      *(uint2*)(Pw + l16 * 72 + i * 16 + quad * 4) = pr;
    }

    float ar[4];
#pragma unroll
    for (int r = 0; r < 4; ++r)
      ar[r] = __shfl(alpha, (lane & 48) | (quad * 4 + r));
#pragma unroll
    for (int jd = 0; jd < 4; ++jd)
#pragma unroll
      for (int r = 0; r < 4; ++r) O[jd][r] *= ar[r];

#pragma unroll
    for (int ks = 0; ks < 2; ++ks) {
      bf16x8 ap = *(const bf16x8*)(Pw + l16 * 72 + ks * 32 + quad * 8);
#pragma unroll
      for (int jd = 0; jd < 4; ++jd) {
        union { unsigned int u[4]; bf16x8 v; } bv;
        int vbase = (jd * 16 + l16) * 35 + ks * 16 + quad * 4;
#pragma unroll
        for (int cc = 0; cc < 4; ++cc) bv.u[cc] = Vt[vbase + cc];
        O[jd] = __builtin_amdgcn_mfma_f32_16x16x32_bf16(ap, bv.v, O[jd], 0, 0, 0);
      }
    }
    __syncthreads();
  }

  float li[4];
#pragma unroll
  for (int r = 0; r < 4; ++r)
    li[r] = 1.f / __shfl(l_i, (lane & 48) | (quad * 4 + r));
#pragma unroll
  for (int jd = 0; jd < 4; ++jd)
#pragma unroll
    for (int r = 0; r < 4; ++r) {
      size_t row = (size_t)b * 2048 + q0 + w * 16 + quad * 4 + r;
      out[row * 1024 + h * 64 + jd * 16 + l16] = f2b(O[jd][r] * li[r]);
    }
}

// ---------------------------------------------------------------------------
extern "C" void kernel_launch(void* const* d_in, const int* in_sizes, int n_in,
                              void* d_out, int out_size, void* d_ws, size_t ws_size,
                              hipStream_t stream) {
  (void)in_sizes; (void)n_in; (void)out_size;
  const void* x     = d_in[0];
  const void* ln1s  = d_in[2];
  const void* ln1b  = d_in[3];
  const void* ln2s  = d_in[4];
  const void* ln2b  = d_in[5];
  const void* w_qkv = d_in[6];
  const void* b_qkv = d_in[7];
  const void* w_ap  = d_in[8];
  const void* b_ap  = d_in[9];
  const void* w_fc  = d_in[10];
  const void* b_fc  = d_in[11];
  const void* w_mp  = d_in[12];
  const void* b_mp  = d_in[13];
  char* ws = (char*)d_ws;

  const int M = 4096, D = 1024, DFF = 4096, QKV3 = 3072;
  size_t off = 0;
  auto alloc = [&](size_t n) { char* p = ws + off; off += n; return p; };
  int* flag            = (int*)alloc(256);
  unsigned short* wT   = (unsigned short*)alloc((size_t)DFF * D * 2);   // 8 MiB
  unsigned short* hbuf = (unsigned short*)alloc((size_t)M * D * 2);     // 8 MiB (LN out / attn out)
  unsigned short* x1   = (unsigned short*)alloc((size_t)M * D * 2);     // 8 MiB
  char* region = alloc((size_t)M * DFF * 2);                            // 32 MiB
  unsigned short* qkvb = (unsigned short*)region;                       // [4096][3072] 24 MiB
  float* P0a = (float*)region;                                          // 16 MiB (after qkvb dead)
  float* P1a = (float*)(region + (size_t)M * D * 4);                    // 16 MiB
  unsigned short* fcb  = (unsigned short*)region;                       // [4096][4096] 32 MiB
  bool mlpSplit = ws_size >= off + (size_t)M * D * 8 + 1024;
  float* P0m = (float*)(ws + off);
  float* P1m = P0m + (size_t)M * D;

  dim3 blk(256);
  detect_k<<<dim3(1), dim3(64), 0, stream>>>((const unsigned short*)x, flag);
  // --- attention branch ---
  transpose_k<<<dim3(QKV3 / 64, D / 64), blk, 0, stream>>>(w_qkv, wT, D, QKV3, flag);
  ln_k<<<dim3(M), blk, 0, stream>>>(x, ln1s, ln1b, hbuf, flag, 1);
  gemm_bt<0><<<dim3(QKV3 / 128, M / 128), blk, 0, stream>>>(hbuf, wT, b_qkv, nullptr, qkvb, M, QKV3, D, flag, 0, 0);
  attn_k<<<dim3(32, 32), blk, 0, stream>>>(qkvb, hbuf);
  transpose_k<<<dim3(D / 64, D / 64), blk, 0, stream>>>(w_ap, wT, D, D, flag);
  gemm_pk<<<dim3(D / 128, M / 128, 2), blk, 0, stream>>>(hbuf, wT, P0a, M, D, D / 2, D);
  reduce2_k<<<dim3(M * D / 1024), blk, 0, stream>>>(P0a, P1a, b_ap, x, x1, D, flag, 1, 0);
  // --- MLP branch ---
  transpose_k<<<dim3(DFF / 64, D / 64), blk, 0, stream>>>(w_fc, wT, D, DFF, flag);
  ln_k<<<dim3(M), blk, 0, stream>>>(x1, ln2s, ln2b, hbuf, flag, 0);
  gemm_bt<1><<<dim3(DFF / 128, M / 128), blk, 0, stream>>>(hbuf, wT, b_fc, nullptr, fcb, M, DFF, D, flag, 0, 0);
  transpose_k<<<dim3(D / 64, DFF / 64), blk, 0, stream>>>(w_mp, wT, DFF, D, flag);
  if (mlpSplit) {
    gemm_pk<<<dim3(D / 128, M / 128, 2), blk, 0, stream>>>(fcb, wT, P0m, M, D, DFF / 2, DFF);
    reduce2_k<<<dim3(M * D / 1024), blk, 0, stream>>>(P0m, P1m, b_mp, x1, d_out, D, flag, 0, 1);
  } else {
    gemm_bt<2><<<dim3(D / 128, M / 128), blk, 0, stream>>>(fcb, wT, b_mp, x1, d_out, M, D, DFF, flag, 0, 1);
  }
}

// Round 7
// 417.355 us; speedup vs baseline: 1.1024x; 1.1024x over previous
//
#include <hip/hip_runtime.h>
#include <hip/hip_bf16.h>
#include <stdint.h>

// ---------------------------------------------------------------------------
// GPT-2 block, runtime dtype-adaptive (fp32 or bf16 external), bf16 internal,
// fp32 accumulate. MI355X / gfx950.
// R7: paired flash-attn restored (perfect per-block balance, 33 iters each)
// + register prefetch of next K/V tile + packed bf16 cvt for P.
// GEMMs keep R6 BK=64 (4x 8KB LDS half-buffers).
// ---------------------------------------------------------------------------

typedef __attribute__((ext_vector_type(8))) short bf16x8;
typedef __attribute__((ext_vector_type(8))) unsigned short u16x8;
typedef __attribute__((ext_vector_type(4))) float f32x4;

#define NEG_BIG -30000.0f
#define EXP2SC 0.18033688011112042f   // 0.125 * log2(e)

__device__ __forceinline__ float b2f(unsigned short u) {
  union { unsigned int i; float f; } c; c.i = ((unsigned int)u) << 16; return c.f;
}
__device__ __forceinline__ unsigned short f2b(float f) {
  union { float f; unsigned int u; } c; c.f = f;
  unsigned int r = c.u + 0x7fffu + ((c.u >> 16) & 1u);   // RNE
  return (unsigned short)(r >> 16);
}
__device__ __forceinline__ unsigned int pk2bf(float a, float b) {
  float2 f; f.x = a; f.y = b;
  union { __hip_bfloat162 h; unsigned int u; } c;
  c.h = __float22bfloat162_rn(f);      // v_cvt_pk_bf16_f32
  return c.u;
}
__device__ __forceinline__ float ldx(const void* p, size_t i, int f32) {
  return f32 ? ((const float*)p)[i] : b2f(((const unsigned short*)p)[i]);
}
__device__ __forceinline__ void gld_lds16(const void* g, void* l) {
  __builtin_amdgcn_global_load_lds(
      (__attribute__((address_space(1))) void*)(void*)g,
      (__attribute__((address_space(3))) void*)l, 16, 0, 0);
}

// ---------------------------------------------------------------------------
__global__ void detect_k(const unsigned short* __restrict__ x, int* __restrict__ flag) {
  int lane = threadIdx.x;
  int cnt = 0;
#pragma unroll
  for (int j = 0; j < 4; ++j) {
    unsigned e = (x[lane * 4 + j] >> 7) & 0xFF;
    if (e >= 100 && e <= 145) cnt++;
  }
#pragma unroll
  for (int off = 32; off; off >>= 1) cnt += __shfl_down(cnt, off);
  if (lane == 0) *flag = (cnt < 220) ? 1 : 0;
}

// ---------------------------------------------------------------------------
// 64x64 tile transpose, adaptive input, bf16 out: out[n*K+k] = in[k*N+n]
// ---------------------------------------------------------------------------
__global__ __launch_bounds__(256) void transpose_k(
    const void* __restrict__ in, unsigned short* __restrict__ out,
    int K, int N, const int* __restrict__ flag) {
  int fm = *flag;
  __shared__ unsigned short tile[64][72];
  int n0 = blockIdx.x * 64, k0 = blockIdx.y * 64;
  int t = threadIdx.x;
  int r = t >> 3, c0 = (t & 7) * 8;
  if (fm) {
    const float* inf = (const float*)in;
#pragma unroll
    for (int p = 0; p < 2; ++p) {
      int k = r + p * 32;
      float4 v0 = *(const float4*)(inf + (size_t)(k0 + k) * N + n0 + c0);
      float4 v1 = *(const float4*)(inf + (size_t)(k0 + k) * N + n0 + c0 + 4);
      tile[k][c0 + 0] = f2b(v0.x); tile[k][c0 + 1] = f2b(v0.y);
      tile[k][c0 + 2] = f2b(v0.z); tile[k][c0 + 3] = f2b(v0.w);
      tile[k][c0 + 4] = f2b(v1.x); tile[k][c0 + 5] = f2b(v1.y);
      tile[k][c0 + 6] = f2b(v1.z); tile[k][c0 + 7] = f2b(v1.w);
    }
  } else {
    const unsigned short* inu = (const unsigned short*)in;
#pragma unroll
    for (int p = 0; p < 2; ++p) {
      int k = r + p * 32;
      u16x8 v = *(const u16x8*)(inu + (size_t)(k0 + k) * N + n0 + c0);
      *(u16x8*)&tile[k][c0] = v;
    }
  }
  __syncthreads();
#pragma unroll
  for (int p = 0; p < 2; ++p) {
    int n = r + p * 32;
    u16x8 v;
#pragma unroll
    for (int j = 0; j < 8; ++j) v[j] = tile[c0 + j][n];
    *(u16x8*)(out + (size_t)(n0 + n) * K + k0 + c0) = v;
  }
}

// ---------------------------------------------------------------------------
// LayerNorm D=1024
// ---------------------------------------------------------------------------
__global__ __launch_bounds__(256) void ln_k(
    const void* __restrict__ x, const void* __restrict__ sc,
    const void* __restrict__ bs, unsigned short* __restrict__ out,
    const int* __restrict__ flag, int xAdap) {
  int fm = *flag;
  int fx = xAdap ? fm : 0;
  int row = blockIdx.x, t = threadIdx.x;
  float f0, f1, f2, f3;
  if (fx) {
    float4 xv = ((const float4*)x)[(size_t)row * 256 + t];
    f0 = xv.x; f1 = xv.y; f2 = xv.z; f3 = xv.w;
  } else {
    ushort4 xv = ((const ushort4*)x)[(size_t)row * 256 + t];
    f0 = b2f(xv.x); f1 = b2f(xv.y); f2 = b2f(xv.z); f3 = b2f(xv.w);
  }
  float s = f0 + f1 + f2 + f3;
  float q = f0 * f0 + f1 * f1 + f2 * f2 + f3 * f3;
#pragma unroll
  for (int off = 32; off; off >>= 1) {
    s += __shfl_down(s, off);
    q += __shfl_down(q, off);
  }
  __shared__ float red[8];
  int w = t >> 6, lane = t & 63;
  if (lane == 0) { red[w] = s; red[w + 4] = q; }
  __syncthreads();
  float S = red[0] + red[1] + red[2] + red[3];
  float Q = red[4] + red[5] + red[6] + red[7];
  float mean = S * (1.f / 1024.f);
  float var = Q * (1.f / 1024.f) - mean * mean;
  float rstd = rsqrtf(var + 1e-5f);
  int c = t * 4;
  ushort4 o;
  o.x = f2b((f0 - mean) * rstd * ldx(sc, c, fm)     + ldx(bs, c, fm));
  o.y = f2b((f1 - mean) * rstd * ldx(sc, c + 1, fm) + ldx(bs, c + 1, fm));
  o.z = f2b((f2 - mean) * rstd * ldx(sc, c + 2, fm) + ldx(bs, c + 2, fm));
  o.w = f2b((f3 - mean) * rstd * ldx(sc, c + 3, fm) + ldx(bs, c + 3, fm));
  ((ushort4*)(out + (size_t)row * 1024))[t] = o;
}

// ---------------------------------------------------------------------------
// GEMM: C[M,N] = A[M,K]*Bt[N,K]^T + bias; EPI: 0=none 1=gelu 2=+res
// 128x128 tile, BK=64 via two 32-col half-buffers per operand.
// ---------------------------------------------------------------------------
template <int EPI>
__global__ __launch_bounds__(256) void gemm_bt(
    const unsigned short* __restrict__ A, const unsigned short* __restrict__ Bt,
    const void* __restrict__ bias, const void* __restrict__ res,
    void* __restrict__ C, int M, int N, int K,
    const int* __restrict__ flag, int resAdap, int outAdap) {
  int fm = *flag;
  int fr = resAdap ? fm : 0;
  int fo = outAdap ? fm : 0;
  __shared__ unsigned short As[2][128 * 32];
  __shared__ unsigned short Bs[2][128 * 32];
  int t = threadIdx.x;
  int bn = blockIdx.x * 128, bm = blockIdx.y * 128;
  int w = t >> 6, lane = t & 63, quad = lane >> 4, l16 = lane & 15;
  int wm = (w >> 1) * 64, wn = (w & 1) * 64;
  f32x4 acc[4][4] = {};

  int c1 = t, c2 = t + 256;
  int r1 = c1 >> 2, e1 = (c1 & 3) * 8;
  int r2 = c2 >> 2, e2 = (c2 & 3) * 8;
  const unsigned short* a1 = A + (size_t)(bm + r1) * K + e1;
  const unsigned short* a2 = A + (size_t)(bm + r2) * K + e2;
  const unsigned short* b1 = Bt + (size_t)(bn + r1) * K + e1;
  const unsigned short* b2 = Bt + (size_t)(bn + r2) * K + e2;

  for (int k0 = 0; k0 < K; k0 += 64) {
    gld_lds16(a1 + k0,      As[0] + c1 * 8);
    gld_lds16(a2 + k0,      As[0] + c2 * 8);
    gld_lds16(a1 + k0 + 32, As[1] + c1 * 8);
    gld_lds16(a2 + k0 + 32, As[1] + c2 * 8);
    gld_lds16(b1 + k0,      Bs[0] + c1 * 8);
    gld_lds16(b2 + k0,      Bs[0] + c2 * 8);
    gld_lds16(b1 + k0 + 32, Bs[1] + c1 * 8);
    gld_lds16(b2 + k0 + 32, Bs[1] + c2 * 8);
    __syncthreads();
#pragma unroll
    for (int h = 0; h < 2; ++h) {
      bf16x8 af[4], bfr[4];
#pragma unroll
      for (int i = 0; i < 4; ++i)
        af[i] = *(const bf16x8*)&As[h][(wm + i * 16 + l16) * 32 + quad * 8];
#pragma unroll
      for (int j = 0; j < 4; ++j)
        bfr[j] = *(const bf16x8*)&Bs[h][(wn + j * 16 + l16) * 32 + quad * 8];
#pragma unroll
      for (int i = 0; i < 4; ++i)
#pragma unroll
        for (int j = 0; j < 4; ++j)
          acc[i][j] = __builtin_amdgcn_mfma_f32_16x16x32_bf16(af[i], bfr[j], acc[i][j], 0, 0, 0);
    }
    __syncthreads();
  }

#pragma unroll
  for (int j = 0; j < 4; ++j) {
    int col = bn + wn + j * 16 + l16;
    float bb = ldx(bias, col, fm);
#pragma unroll
    for (int i = 0; i < 4; ++i) {
      int row0 = bm + wm + i * 16 + quad * 4;
#pragma unroll
      for (int r = 0; r < 4; ++r) {
        float v = acc[i][j][r] + bb;
        if (EPI == 1) {
          float u = 0.7978845608f * (v + 0.044715f * v * v * v);
          float e = __expf(2.f * u);          // tanh(u) = 1 - 2/(e^{2u}+1)
          float th = 1.f - 2.f / (e + 1.f);
          v = 0.5f * v * (1.f + th);
        } else if (EPI == 2) {
          v += ldx(res, (size_t)(row0 + r) * N + col, fr);
        }
        size_t idx = (size_t)(row0 + r) * N + col;
        if (fo) ((float*)C)[idx] = v;
        else    ((unsigned short*)C)[idx] = f2b(v);
      }
    }
  }
}

// ---------------------------------------------------------------------------
// Split-K GEMM: P[z][M,N] = A[:, z*Kh:(z+1)*Kh] * Bt^T (fp32, no epilogue)
// ---------------------------------------------------------------------------
__global__ __launch_bounds__(256) void gemm_pk(
    const unsigned short* __restrict__ A, const unsigned short* __restrict__ Bt,
    float* __restrict__ P, int M, int N, int Kh, int Kfull) {
  __shared__ unsigned short As[2][128 * 32];
  __shared__ unsigned short Bs[2][128 * 32];
  int t = threadIdx.x;
  int bn = blockIdx.x * 128, bm = blockIdx.y * 128;
  int koff = blockIdx.z * Kh;
  float* Pz = P + (size_t)blockIdx.z * M * N;
  int w = t >> 6, lane = t & 63, quad = lane >> 4, l16 = lane & 15;
  int wm = (w >> 1) * 64, wn = (w & 1) * 64;
  f32x4 acc[4][4] = {};

  int c1 = t, c2 = t + 256;
  int r1 = c1 >> 2, e1 = (c1 & 3) * 8;
  int r2 = c2 >> 2, e2 = (c2 & 3) * 8;
  const unsigned short* a1 = A + (size_t)(bm + r1) * Kfull + koff + e1;
  const unsigned short* a2 = A + (size_t)(bm + r2) * Kfull + koff + e2;
  const unsigned short* b1 = Bt + (size_t)(bn + r1) * Kfull + koff + e1;
  const unsigned short* b2 = Bt + (size_t)(bn + r2) * Kfull + koff + e2;

  for (int k0 = 0; k0 < Kh; k0 += 64) {
    gld_lds16(a1 + k0,      As[0] + c1 * 8);
    gld_lds16(a2 + k0,      As[0] + c2 * 8);
    gld_lds16(a1 + k0 + 32, As[1] + c1 * 8);
    gld_lds16(a2 + k0 + 32, As[1] + c2 * 8);
    gld_lds16(b1 + k0,      Bs[0] + c1 * 8);
    gld_lds16(b2 + k0,      Bs[0] + c2 * 8);
    gld_lds16(b1 + k0 + 32, Bs[1] + c1 * 8);
    gld_lds16(b2 + k0 + 32, Bs[1] + c2 * 8);
    __syncthreads();
#pragma unroll
    for (int h = 0; h < 2; ++h) {
      bf16x8 af[4], bfr[4];
#pragma unroll
      for (int i = 0; i < 4; ++i)
        af[i] = *(const bf16x8*)&As[h][(wm + i * 16 + l16) * 32 + quad * 8];
#pragma unroll
      for (int j = 0; j < 4; ++j)
        bfr[j] = *(const bf16x8*)&Bs[h][(wn + j * 16 + l16) * 32 + quad * 8];
#pragma unroll
      for (int i = 0; i < 4; ++i)
#pragma unroll
        for (int j = 0; j < 4; ++j)
          acc[i][j] = __builtin_amdgcn_mfma_f32_16x16x32_bf16(af[i], bfr[j], acc[i][j], 0, 0, 0);
    }
    __syncthreads();
  }

#pragma unroll
  for (int j = 0; j < 4; ++j) {
    int col = bn + wn + j * 16 + l16;
#pragma unroll
    for (int i = 0; i < 4; ++i) {
      int row0 = bm + wm + i * 16 + quad * 4;
#pragma unroll
      for (int r = 0; r < 4; ++r)
        Pz[(size_t)(row0 + r) * N + col] = acc[i][j][r];
    }
  }
}

// ---------------------------------------------------------------------------
// reduce: out = P0 + P1 + bias (+ res), N power of two
// ---------------------------------------------------------------------------
__global__ __launch_bounds__(256) void reduce2_k(
    const float* __restrict__ P0, const float* __restrict__ P1,
    const void* __restrict__ bias, const void* __restrict__ res,
    void* __restrict__ out, int N,
    const int* __restrict__ flag, int resAdap, int outAdap) {
  int fm = *flag;
  int fr = resAdap ? fm : 0;
  int fo = outAdap ? fm : 0;
  size_t idx = ((size_t)blockIdx.x * 256 + threadIdx.x) * 4;
  float4 p0 = *(const float4*)(P0 + idx);
  float4 p1 = *(const float4*)(P1 + idx);
  int col = (int)(idx & (size_t)(N - 1));
  float v0 = p0.x + p1.x + ldx(bias, col, fm)     + ldx(res, idx, fr);
  float v1 = p0.y + p1.y + ldx(bias, col + 1, fm) + ldx(res, idx + 1, fr);
  float v2 = p0.z + p1.z + ldx(bias, col + 2, fm) + ldx(res, idx + 2, fr);
  float v3 = p0.w + p1.w + ldx(bias, col + 3, fm) + ldx(res, idx + 3, fr);
  if (fo) {
    float4 o; o.x = v0; o.y = v1; o.z = v2; o.w = v3;
    *(float4*)((float*)out + idx) = o;
  } else {
    ushort4 o; o.x = f2b(v0); o.y = f2b(v1); o.z = f2b(v2); o.w = f2b(v3);
    *(ushort4*)((unsigned short*)out + idx) = o;
  }
}

// ---------------------------------------------------------------------------
// Flash attention, causal, S^T formulation, PAIRED q-tiles (pi, 31-pi):
// every block does exactly 33 kt-iters -> perfect static balance.
// Register prefetch of next K/V tile hides global latency behind compute.
// ---------------------------------------------------------------------------
__global__ __launch_bounds__(256) void attn_k(
    const unsigned short* __restrict__ qkv, unsigned short* __restrict__ out) {
  __shared__ unsigned short Ks[64 * 72];
  __shared__ unsigned int   Vt[64 * 35];
  __shared__ unsigned short Ps[4 * 16 * 72];
  int t = threadIdx.x, w = t >> 6, lane = t & 63, quad = lane >> 4, l16 = lane & 15;
  int pi = blockIdx.x, bh = blockIdx.y, b = bh >> 4, h = bh & 15;
  const unsigned short* base = qkv + (size_t)b * 2048 * 3072 + h * 64;
  unsigned short* Pw = Ps + w * 16 * 72;
  int srow = t >> 3, d0 = (t & 7) * 8;

#pragma unroll 1
  for (int half = 0; half < 2; ++half) {
    int qt = half ? (31 - pi) : pi;
    int q0 = qt * 64;
    int qrel = w * 16 + l16;
    const unsigned short* qp = base + (size_t)(q0 + qrel) * 3072;
    bf16x8 bq0 = *(const bf16x8*)(qp + quad * 8);
    bf16x8 bq1 = *(const bf16x8*)(qp + 32 + quad * 8);
    float m_i = NEG_BIG, l_i = 0.f;
    f32x4 O[4] = {};

    // prefetch kt=0 K/V into regs
    u16x8 kA, kB, vA, vB;
    {
      const unsigned short* kb = base;
      kA = *(const u16x8*)(kb + (size_t)srow * 3072 + 1024 + d0);
      kB = *(const u16x8*)(kb + (size_t)(srow + 32) * 3072 + 1024 + d0);
      vA = *(const u16x8*)(kb + (size_t)(2 * srow) * 3072 + 2048 + d0);
      vB = *(const u16x8*)(kb + (size_t)(2 * srow + 1) * 3072 + 2048 + d0);
    }

#pragma unroll 1
    for (int kt = 0; kt <= qt; ++kt) {
      // write staged regs -> LDS
      *(u16x8*)&Ks[srow * 72 + d0] = kA;
      *(u16x8*)&Ks[(srow + 32) * 72 + d0] = kB;
#pragma unroll
      for (int j = 0; j < 8; ++j)
        Vt[(d0 + j) * 35 + srow] = (unsigned int)vA[j] | ((unsigned int)vB[j] << 16);
      __syncthreads();

      // prefetch next tile while computing this one
      if (kt < qt) {
        const unsigned short* kb = base + (size_t)((kt + 1) * 64) * 3072;
        kA = *(const u16x8*)(kb + (size_t)srow * 3072 + 1024 + d0);
        kB = *(const u16x8*)(kb + (size_t)(srow + 32) * 3072 + 1024 + d0);
        vA = *(const u16x8*)(kb + (size_t)(2 * srow) * 3072 + 2048 + d0);
        vB = *(const u16x8*)(kb + (size_t)(2 * srow + 1) * 3072 + 2048 + d0);
      }

      // S^T = K . Q^T : per wave [64 s][16 q]
      f32x4 ST[4];
#pragma unroll
      for (int i = 0; i < 4; ++i) {
        bf16x8 ak0 = *(const bf16x8*)&Ks[(i * 16 + l16) * 72 + quad * 8];
        bf16x8 ak1 = *(const bf16x8*)&Ks[(i * 16 + l16) * 72 + 32 + quad * 8];
        f32x4 z = {};
        z = __builtin_amdgcn_mfma_f32_16x16x32_bf16(ak0, bq0, z, 0, 0, 0);
        ST[i] = __builtin_amdgcn_mfma_f32_16x16x32_bf16(ak1, bq1, z, 0, 0, 0);
      }

      bool dm = (kt == qt);
      float p[4][4];
      float mx = NEG_BIG;
#pragma unroll
      for (int i = 0; i < 4; ++i)
#pragma unroll
        for (int r = 0; r < 4; ++r) {
          float v = ST[i][r] * EXP2SC;
          int srel = i * 16 + quad * 4 + r;
          if (dm && srel > qrel) v = NEG_BIG;
          p[i][r] = v;
          mx = fmaxf(mx, v);
        }
      mx = fmaxf(mx, __shfl_xor(mx, 16));
      mx = fmaxf(mx, __shfl_xor(mx, 32));
      float mn = fmaxf(m_i, mx);
      float alpha = exp2f(m_i - mn);
      m_i = mn;
      float sum = 0.f;
#pragma unroll
      for (int i = 0; i < 4; ++i)
#pragma unroll
        for (int r = 0; r < 4; ++r) {
          float e = exp2f(p[i][r] - mn);
          p[i][r] = e;
          sum += e;
        }
      sum += __shfl_xor(sum, 16);
      sum += __shfl_xor(sum, 32);
      l_i = alpha * l_i + sum;

      // P[q=l16][s] : packed cvt + 4x ds_write_b64 (own wave's region)
#pragma unroll
      for (int i = 0; i < 4; ++i) {
        uint2 pr;
        pr.x = pk2bf(p[i][0], p[i][1]);
        pr.y = pk2bf(p[i][2], p[i][3]);
        *(uint2*)(Pw + l16 * 72 + i * 16 + quad * 4) = pr;
      }

      float ar[4];
#pragma unroll
      for (int r = 0; r < 4; ++r)
        ar[r] = __shfl(alpha, (lane & 48) | (quad * 4 + r));
#pragma unroll
      for (int jd = 0; jd < 4; ++jd)
#pragma unroll
        for (int r = 0; r < 4; ++r) O[jd][r] *= ar[r];

      // O += P . V
#pragma unroll
      for (int ks = 0; ks < 2; ++ks) {
        bf16x8 ap = *(const bf16x8*)(Pw + l16 * 72 + ks * 32 + quad * 8);
#pragma unroll
        for (int jd = 0; jd < 4; ++jd) {
          union { unsigned int u[4]; bf16x8 v; } bv;
          int vbase = (jd * 16 + l16) * 35 + ks * 16 + quad * 4;
#pragma unroll
          for (int cc = 0; cc < 4; ++cc) bv.u[cc] = Vt[vbase + cc];
          O[jd] = __builtin_amdgcn_mfma_f32_16x16x32_bf16(ap, bv.v, O[jd], 0, 0, 0);
        }
      }
      __syncthreads();   // Ks/Vt consumed before restage
    }

    float li[4];
#pragma unroll
    for (int r = 0; r < 4; ++r)
      li[r] = 1.f / __shfl(l_i, (lane & 48) | (quad * 4 + r));
#pragma unroll
    for (int jd = 0; jd < 4; ++jd)
#pragma unroll
      for (int r = 0; r < 4; ++r) {
        size_t row = (size_t)b * 2048 + q0 + w * 16 + quad * 4 + r;
        out[row * 1024 + h * 64 + jd * 16 + l16] = f2b(O[jd][r] * li[r]);
      }
  }
}

// ---------------------------------------------------------------------------
extern "C" void kernel_launch(void* const* d_in, const int* in_sizes, int n_in,
                              void* d_out, int out_size, void* d_ws, size_t ws_size,
                              hipStream_t stream) {
  (void)in_sizes; (void)n_in; (void)out_size;
  const void* x     = d_in[0];
  const void* ln1s  = d_in[2];
  const void* ln1b  = d_in[3];
  const void* ln2s  = d_in[4];
  const void* ln2b  = d_in[5];
  const void* w_qkv = d_in[6];
  const void* b_qkv = d_in[7];
  const void* w_ap  = d_in[8];
  const void* b_ap  = d_in[9];
  const void* w_fc  = d_in[10];
  const void* b_fc  = d_in[11];
  const void* w_mp  = d_in[12];
  const void* b_mp  = d_in[13];
  char* ws = (char*)d_ws;

  const int M = 4096, D = 1024, DFF = 4096, QKV3 = 3072;
  size_t off = 0;
  auto alloc = [&](size_t n) { char* p = ws + off; off += n; return p; };
  int* flag            = (int*)alloc(256);
  unsigned short* wT   = (unsigned short*)alloc((size_t)DFF * D * 2);   // 8 MiB
  unsigned short* hbuf = (unsigned short*)alloc((size_t)M * D * 2);     // 8 MiB (LN out / attn out)
  unsigned short* x1   = (unsigned short*)alloc((size_t)M * D * 2);     // 8 MiB
  char* region = alloc((size_t)M * DFF * 2);                            // 32 MiB
  unsigned short* qkvb = (unsigned short*)region;                       // [4096][3072] 24 MiB
  float* P0a = (float*)region;                                          // 16 MiB (after qkvb dead)
  float* P1a = (float*)(region + (size_t)M * D * 4);                    // 16 MiB
  unsigned short* fcb  = (unsigned short*)region;                       // [4096][4096] 32 MiB
  bool mlpSplit = ws_size >= off + (size_t)M * D * 8 + 1024;
  float* P0m = (float*)(ws + off);
  float* P1m = P0m + (size_t)M * D;

  dim3 blk(256);
  detect_k<<<dim3(1), dim3(64), 0, stream>>>((const unsigned short*)x, flag);
  // --- attention branch ---
  transpose_k<<<dim3(QKV3 / 64, D / 64), blk, 0, stream>>>(w_qkv, wT, D, QKV3, flag);
  ln_k<<<dim3(M), blk, 0, stream>>>(x, ln1s, ln1b, hbuf, flag, 1);
  gemm_bt<0><<<dim3(QKV3 / 128, M / 128), blk, 0, stream>>>(hbuf, wT, b_qkv, nullptr, qkvb, M, QKV3, D, flag, 0, 0);
  attn_k<<<dim3(16, 32), blk, 0, stream>>>(qkvb, hbuf);
  transpose_k<<<dim3(D / 64, D / 64), blk, 0, stream>>>(w_ap, wT, D, D, flag);
  gemm_pk<<<dim3(D / 128, M / 128, 2), blk, 0, stream>>>(hbuf, wT, P0a, M, D, D / 2, D);
  reduce2_k<<<dim3(M * D / 1024), blk, 0, stream>>>(P0a, P1a, b_ap, x, x1, D, flag, 1, 0);
  // --- MLP branch ---
  transpose_k<<<dim3(DFF / 64, D / 64), blk, 0, stream>>>(w_fc, wT, D, DFF, flag);
  ln_k<<<dim3(M), blk, 0, stream>>>(x1, ln2s, ln2b, hbuf, flag, 0);
  gemm_bt<1><<<dim3(DFF / 128, M / 128), blk, 0, stream>>>(hbuf, wT, b_fc, nullptr, fcb, M, DFF, D, flag, 0, 0);
  transpose_k<<<dim3(D / 64, DFF / 64), blk, 0, stream>>>(w_mp, wT, DFF, D, flag);
  if (mlpSplit) {
    gemm_pk<<<dim3(D / 128, M / 128, 2), blk, 0, stream>>>(fcb, wT, P0m, M, D, DFF / 2, DFF);
    reduce2_k<<<dim3(M * D / 1024), blk, 0, stream>>>(P0m, P1m, b_mp, x1, d_out, D, flag, 0, 1);
  } else {
    gemm_bt<2><<<dim3(D / 128, M / 128), blk, 0, stream>>>(fcb, wT, b_mp, x1, d_out, M, D, DFF, flag, 0, 1);
  }
}

// Round 8
// 413.660 us; speedup vs baseline: 1.1123x; 1.0089x over previous
//
#include <hip/hip_runtime.h>
#include <hip/hip_bf16.h>
#include <stdint.h>

// ---------------------------------------------------------------------------
// GPT-2 block, runtime dtype-adaptive (fp32 or bf16 external), bf16 internal,
// fp32 accumulate. MI355X / gfx950.
// R8: GEMM K-loop restructured to register-prefetch + double-buffered LDS +
// SINGLE barrier per K-step (no global_load_lds -> no vmcnt(0) barrier drain).
// Attention keeps R7 (paired tiles + reg prefetch).
// ---------------------------------------------------------------------------

typedef __attribute__((ext_vector_type(8))) short bf16x8;
typedef __attribute__((ext_vector_type(8))) unsigned short u16x8;
typedef __attribute__((ext_vector_type(4))) float f32x4;

#define NEG_BIG -30000.0f
#define EXP2SC 0.18033688011112042f   // 0.125 * log2(e)

__device__ __forceinline__ float b2f(unsigned short u) {
  union { unsigned int i; float f; } c; c.i = ((unsigned int)u) << 16; return c.f;
}
__device__ __forceinline__ unsigned short f2b(float f) {
  union { float f; unsigned int u; } c; c.f = f;
  unsigned int r = c.u + 0x7fffu + ((c.u >> 16) & 1u);   // RNE
  return (unsigned short)(r >> 16);
}
__device__ __forceinline__ unsigned int pk2bf(float a, float b) {
  float2 f; f.x = a; f.y = b;
  union { __hip_bfloat162 h; unsigned int u; } c;
  c.h = __float22bfloat162_rn(f);      // v_cvt_pk_bf16_f32
  return c.u;
}
__device__ __forceinline__ float ldx(const void* p, size_t i, int f32) {
  return f32 ? ((const float*)p)[i] : b2f(((const unsigned short*)p)[i]);
}

// ---------------------------------------------------------------------------
__global__ void detect_k(const unsigned short* __restrict__ x, int* __restrict__ flag) {
  int lane = threadIdx.x;
  int cnt = 0;
#pragma unroll
  for (int j = 0; j < 4; ++j) {
    unsigned e = (x[lane * 4 + j] >> 7) & 0xFF;
    if (e >= 100 && e <= 145) cnt++;
  }
#pragma unroll
  for (int off = 32; off; off >>= 1) cnt += __shfl_down(cnt, off);
  if (lane == 0) *flag = (cnt < 220) ? 1 : 0;
}

// ---------------------------------------------------------------------------
// 64x64 tile transpose, adaptive input, bf16 out: out[n*K+k] = in[k*N+n]
// ---------------------------------------------------------------------------
__global__ __launch_bounds__(256) void transpose_k(
    const void* __restrict__ in, unsigned short* __restrict__ out,
    int K, int N, const int* __restrict__ flag) {
  int fm = *flag;
  __shared__ unsigned short tile[64][72];
  int n0 = blockIdx.x * 64, k0 = blockIdx.y * 64;
  int t = threadIdx.x;
  int r = t >> 3, c0 = (t & 7) * 8;
  if (fm) {
    const float* inf = (const float*)in;
#pragma unroll
    for (int p = 0; p < 2; ++p) {
      int k = r + p * 32;
      float4 v0 = *(const float4*)(inf + (size_t)(k0 + k) * N + n0 + c0);
      float4 v1 = *(const float4*)(inf + (size_t)(k0 + k) * N + n0 + c0 + 4);
      tile[k][c0 + 0] = f2b(v0.x); tile[k][c0 + 1] = f2b(v0.y);
      tile[k][c0 + 2] = f2b(v0.z); tile[k][c0 + 3] = f2b(v0.w);
      tile[k][c0 + 4] = f2b(v1.x); tile[k][c0 + 5] = f2b(v1.y);
      tile[k][c0 + 6] = f2b(v1.z); tile[k][c0 + 7] = f2b(v1.w);
    }
  } else {
    const unsigned short* inu = (const unsigned short*)in;
#pragma unroll
    for (int p = 0; p < 2; ++p) {
      int k = r + p * 32;
      u16x8 v = *(const u16x8*)(inu + (size_t)(k0 + k) * N + n0 + c0);
      *(u16x8*)&tile[k][c0] = v;
    }
  }
  __syncthreads();
#pragma unroll
  for (int p = 0; p < 2; ++p) {
    int n = r + p * 32;
    u16x8 v;
#pragma unroll
    for (int j = 0; j < 8; ++j) v[j] = tile[c0 + j][n];
    *(u16x8*)(out + (size_t)(n0 + n) * K + k0 + c0) = v;
  }
}

// ---------------------------------------------------------------------------
// LayerNorm D=1024
// ---------------------------------------------------------------------------
__global__ __launch_bounds__(256) void ln_k(
    const void* __restrict__ x, const void* __restrict__ sc,
    const void* __restrict__ bs, unsigned short* __restrict__ out,
    const int* __restrict__ flag, int xAdap) {
  int fm = *flag;
  int fx = xAdap ? fm : 0;
  int row = blockIdx.x, t = threadIdx.x;
  float f0, f1, f2, f3;
  if (fx) {
    float4 xv = ((const float4*)x)[(size_t)row * 256 + t];
    f0 = xv.x; f1 = xv.y; f2 = xv.z; f3 = xv.w;
  } else {
    ushort4 xv = ((const ushort4*)x)[(size_t)row * 256 + t];
    f0 = b2f(xv.x); f1 = b2f(xv.y); f2 = b2f(xv.z); f3 = b2f(xv.w);
  }
  float s = f0 + f1 + f2 + f3;
  float q = f0 * f0 + f1 * f1 + f2 * f2 + f3 * f3;
#pragma unroll
  for (int off = 32; off; off >>= 1) {
    s += __shfl_down(s, off);
    q += __shfl_down(q, off);
  }
  __shared__ float red[8];
  int w = t >> 6, lane = t & 63;
  if (lane == 0) { red[w] = s; red[w + 4] = q; }
  __syncthreads();
  float S = red[0] + red[1] + red[2] + red[3];
  float Q = red[4] + red[5] + red[6] + red[7];
  float mean = S * (1.f / 1024.f);
  float var = Q * (1.f / 1024.f) - mean * mean;
  float rstd = rsqrtf(var + 1e-5f);
  int c = t * 4;
  ushort4 o;
  o.x = f2b((f0 - mean) * rstd * ldx(sc, c, fm)     + ldx(bs, c, fm));
  o.y = f2b((f1 - mean) * rstd * ldx(sc, c + 1, fm) + ldx(bs, c + 1, fm));
  o.z = f2b((f2 - mean) * rstd * ldx(sc, c + 2, fm) + ldx(bs, c + 2, fm));
  o.w = f2b((f3 - mean) * rstd * ldx(sc, c + 3, fm) + ldx(bs, c + 3, fm));
  ((ushort4*)(out + (size_t)row * 1024))[t] = o;
}

// ---------------------------------------------------------------------------
// GEMM: C[M,N] = A[M,K]*Bt[N,K]^T + bias; EPI: 0=none 1=gelu 2=+res
// 128x128 tile, BK=32, double-buffered LDS, register-prefetch staging,
// ONE barrier per K-step. Writer of buf[i] at iter i+2 passes sync_{i+1}
// only after all readers of buf[i] (iter i) arrived there -> safe.
// ---------------------------------------------------------------------------
template <int EPI>
__global__ __launch_bounds__(256) void gemm_bt(
    const unsigned short* __restrict__ A, const unsigned short* __restrict__ Bt,
    const void* __restrict__ bias, const void* __restrict__ res,
    void* __restrict__ C, int M, int N, int K,
    const int* __restrict__ flag, int resAdap, int outAdap) {
  int fm = *flag;
  int fr = resAdap ? fm : 0;
  int fo = outAdap ? fm : 0;
  __shared__ unsigned short As[2][128 * 32];
  __shared__ unsigned short Bs[2][128 * 32];
  int t = threadIdx.x;
  int bn = blockIdx.x * 128, bm = blockIdx.y * 128;
  int w = t >> 6, lane = t & 63, quad = lane >> 4, l16 = lane & 15;
  int wm = (w >> 1) * 64, wn = (w & 1) * 64;
  f32x4 acc[4][4] = {};

  int c1 = t, c2 = t + 256;
  int r1 = c1 >> 2, e1 = (c1 & 3) * 8;
  int r2 = c2 >> 2, e2 = (c2 & 3) * 8;
  const unsigned short* a1 = A + (size_t)(bm + r1) * K + e1;
  const unsigned short* a2 = A + (size_t)(bm + r2) * K + e2;
  const unsigned short* b1 = Bt + (size_t)(bn + r1) * K + e1;
  const unsigned short* b2 = Bt + (size_t)(bn + r2) * K + e2;

  u16x8 va1 = *(const u16x8*)a1;
  u16x8 va2 = *(const u16x8*)a2;
  u16x8 vb1 = *(const u16x8*)b1;
  u16x8 vb2 = *(const u16x8*)b2;

  int nIter = K >> 5;
  for (int it = 0; it < nIter; ++it) {
    unsigned short* Ab = As[it & 1];
    unsigned short* Bb = Bs[it & 1];
    *(u16x8*)(Ab + c1 * 8) = va1;
    *(u16x8*)(Ab + c2 * 8) = va2;
    *(u16x8*)(Bb + c1 * 8) = vb1;
    *(u16x8*)(Bb + c2 * 8) = vb2;
    __syncthreads();
    if (it + 1 < nIter) {
      int k0 = (it + 1) << 5;
      va1 = *(const u16x8*)(a1 + k0);
      va2 = *(const u16x8*)(a2 + k0);
      vb1 = *(const u16x8*)(b1 + k0);
      vb2 = *(const u16x8*)(b2 + k0);
    }
    bf16x8 af[4], bfr[4];
#pragma unroll
    for (int i = 0; i < 4; ++i)
      af[i] = *(const bf16x8*)&Ab[(wm + i * 16 + l16) * 32 + quad * 8];
#pragma unroll
    for (int j = 0; j < 4; ++j)
      bfr[j] = *(const bf16x8*)&Bb[(wn + j * 16 + l16) * 32 + quad * 8];
#pragma unroll
    for (int i = 0; i < 4; ++i)
#pragma unroll
      for (int j = 0; j < 4; ++j)
        acc[i][j] = __builtin_amdgcn_mfma_f32_16x16x32_bf16(af[i], bfr[j], acc[i][j], 0, 0, 0);
    // no trailing barrier: next iter writes the other buffer
  }

#pragma unroll
  for (int j = 0; j < 4; ++j) {
    int col = bn + wn + j * 16 + l16;
    float bb = ldx(bias, col, fm);
#pragma unroll
    for (int i = 0; i < 4; ++i) {
      int row0 = bm + wm + i * 16 + quad * 4;
#pragma unroll
      for (int r = 0; r < 4; ++r) {
        float v = acc[i][j][r] + bb;
        if (EPI == 1) {
          float u = 0.7978845608f * (v + 0.044715f * v * v * v);
          float e = __expf(2.f * u);          // tanh(u) = 1 - 2/(e^{2u}+1)
          float th = 1.f - 2.f / (e + 1.f);
          v = 0.5f * v * (1.f + th);
        } else if (EPI == 2) {
          v += ldx(res, (size_t)(row0 + r) * N + col, fr);
        }
        size_t idx = (size_t)(row0 + r) * N + col;
        if (fo) ((float*)C)[idx] = v;
        else    ((unsigned short*)C)[idx] = f2b(v);
      }
    }
  }
}

// ---------------------------------------------------------------------------
// Split-K GEMM: P[z][M,N] = A[:, z*Kh:(z+1)*Kh] * Bt^T (fp32, no epilogue)
// Same single-barrier dbuf reg-prefetch structure.
// ---------------------------------------------------------------------------
__global__ __launch_bounds__(256) void gemm_pk(
    const unsigned short* __restrict__ A, const unsigned short* __restrict__ Bt,
    float* __restrict__ P, int M, int N, int Kh, int Kfull) {
  __shared__ unsigned short As[2][128 * 32];
  __shared__ unsigned short Bs[2][128 * 32];
  int t = threadIdx.x;
  int bn = blockIdx.x * 128, bm = blockIdx.y * 128;
  int koff = blockIdx.z * Kh;
  float* Pz = P + (size_t)blockIdx.z * M * N;
  int w = t >> 6, lane = t & 63, quad = lane >> 4, l16 = lane & 15;
  int wm = (w >> 1) * 64, wn = (w & 1) * 64;
  f32x4 acc[4][4] = {};

  int c1 = t, c2 = t + 256;
  int r1 = c1 >> 2, e1 = (c1 & 3) * 8;
  int r2 = c2 >> 2, e2 = (c2 & 3) * 8;
  const unsigned short* a1 = A + (size_t)(bm + r1) * Kfull + koff + e1;
  const unsigned short* a2 = A + (size_t)(bm + r2) * Kfull + koff + e2;
  const unsigned short* b1 = Bt + (size_t)(bn + r1) * Kfull + koff + e1;
  const unsigned short* b2 = Bt + (size_t)(bn + r2) * Kfull + koff + e2;

  u16x8 va1 = *(const u16x8*)a1;
  u16x8 va2 = *(const u16x8*)a2;
  u16x8 vb1 = *(const u16x8*)b1;
  u16x8 vb2 = *(const u16x8*)b2;

  int nIter = Kh >> 5;
  for (int it = 0; it < nIter; ++it) {
    unsigned short* Ab = As[it & 1];
    unsigned short* Bb = Bs[it & 1];
    *(u16x8*)(Ab + c1 * 8) = va1;
    *(u16x8*)(Ab + c2 * 8) = va2;
    *(u16x8*)(Bb + c1 * 8) = vb1;
    *(u16x8*)(Bb + c2 * 8) = vb2;
    __syncthreads();
    if (it + 1 < nIter) {
      int k0 = (it + 1) << 5;
      va1 = *(const u16x8*)(a1 + k0);
      va2 = *(const u16x8*)(a2 + k0);
      vb1 = *(const u16x8*)(b1 + k0);
      vb2 = *(const u16x8*)(b2 + k0);
    }
    bf16x8 af[4], bfr[4];
#pragma unroll
    for (int i = 0; i < 4; ++i)
      af[i] = *(const bf16x8*)&Ab[(wm + i * 16 + l16) * 32 + quad * 8];
#pragma unroll
    for (int j = 0; j < 4; ++j)
      bfr[j] = *(const bf16x8*)&Bb[(wn + j * 16 + l16) * 32 + quad * 8];
#pragma unroll
    for (int i = 0; i < 4; ++i)
#pragma unroll
      for (int j = 0; j < 4; ++j)
        acc[i][j] = __builtin_amdgcn_mfma_f32_16x16x32_bf16(af[i], bfr[j], acc[i][j], 0, 0, 0);
  }

#pragma unroll
  for (int j = 0; j < 4; ++j) {
    int col = bn + wn + j * 16 + l16;
#pragma unroll
    for (int i = 0; i < 4; ++i) {
      int row0 = bm + wm + i * 16 + quad * 4;
#pragma unroll
      for (int r = 0; r < 4; ++r)
        Pz[(size_t)(row0 + r) * N + col] = acc[i][j][r];
    }
  }
}

// ---------------------------------------------------------------------------
// reduce: out = P0 + P1 + bias (+ res), N power of two
// ---------------------------------------------------------------------------
__global__ __launch_bounds__(256) void reduce2_k(
    const float* __restrict__ P0, const float* __restrict__ P1,
    const void* __restrict__ bias, const void* __restrict__ res,
    void* __restrict__ out, int N,
    const int* __restrict__ flag, int resAdap, int outAdap) {
  int fm = *flag;
  int fr = resAdap ? fm : 0;
  int fo = outAdap ? fm : 0;
  size_t idx = ((size_t)blockIdx.x * 256 + threadIdx.x) * 4;
  float4 p0 = *(const float4*)(P0 + idx);
  float4 p1 = *(const float4*)(P1 + idx);
  int col = (int)(idx & (size_t)(N - 1));
  float v0 = p0.x + p1.x + ldx(bias, col, fm)     + ldx(res, idx, fr);
  float v1 = p0.y + p1.y + ldx(bias, col + 1, fm) + ldx(res, idx + 1, fr);
  float v2 = p0.z + p1.z + ldx(bias, col + 2, fm) + ldx(res, idx + 2, fr);
  float v3 = p0.w + p1.w + ldx(bias, col + 3, fm) + ldx(res, idx + 3, fr);
  if (fo) {
    float4 o; o.x = v0; o.y = v1; o.z = v2; o.w = v3;
    *(float4*)((float*)out + idx) = o;
  } else {
    ushort4 o; o.x = f2b(v0); o.y = f2b(v1); o.z = f2b(v2); o.w = f2b(v3);
    *(ushort4*)((unsigned short*)out + idx) = o;
  }
}

// ---------------------------------------------------------------------------
// Flash attention, causal, S^T formulation, paired q-tiles (pi, 31-pi),
// register prefetch of next K/V tile. (R7, unchanged)
// ---------------------------------------------------------------------------
__global__ __launch_bounds__(256) void attn_k(
    const unsigned short* __restrict__ qkv, unsigned short* __restrict__ out) {
  __shared__ unsigned short Ks[64 * 72];
  __shared__ unsigned int   Vt[64 * 35];
  __shared__ unsigned short Ps[4 * 16 * 72];
  int t = threadIdx.x, w = t >> 6, lane = t & 63, quad = lane >> 4, l16 = lane & 15;
  int pi = blockIdx.x, bh = blockIdx.y, b = bh >> 4, h = bh & 15;
  const unsigned short* base = qkv + (size_t)b * 2048 * 3072 + h * 64;
  unsigned short* Pw = Ps + w * 16 * 72;
  int srow = t >> 3, d0 = (t & 7) * 8;

#pragma unroll 1
  for (int half = 0; half < 2; ++half) {
    int qt = half ? (31 - pi) : pi;
    int q0 = qt * 64;
    int qrel = w * 16 + l16;
    const unsigned short* qp = base + (size_t)(q0 + qrel) * 3072;
    bf16x8 bq0 = *(const bf16x8*)(qp + quad * 8);
    bf16x8 bq1 = *(const bf16x8*)(qp + 32 + quad * 8);
    float m_i = NEG_BIG, l_i = 0.f;
    f32x4 O[4] = {};

    u16x8 kA, kB, vA, vB;
    {
      const unsigned short* kb = base;
      kA = *(const u16x8*)(kb + (size_t)srow * 3072 + 1024 + d0);
      kB = *(const u16x8*)(kb + (size_t)(srow + 32) * 3072 + 1024 + d0);
      vA = *(const u16x8*)(kb + (size_t)(2 * srow) * 3072 + 2048 + d0);
      vB = *(const u16x8*)(kb + (size_t)(2 * srow + 1) * 3072 + 2048 + d0);
    }

#pragma unroll 1
    for (int kt = 0; kt <= qt; ++kt) {
      *(u16x8*)&Ks[srow * 72 + d0] = kA;
      *(u16x8*)&Ks[(srow + 32) * 72 + d0] = kB;
#pragma unroll
      for (int j = 0; j < 8; ++j)
        Vt[(d0 + j) * 35 + srow] = (unsigned int)vA[j] | ((unsigned int)vB[j] << 16);
      __syncthreads();

      if (kt < qt) {
        const unsigned short* kb = base + (size_t)((kt + 1) * 64) * 3072;
        kA = *(const u16x8*)(kb + (size_t)srow * 3072 + 1024 + d0);
        kB = *(const u16x8*)(kb + (size_t)(srow + 32) * 3072 + 1024 + d0);
        vA = *(const u16x8*)(kb + (size_t)(2 * srow) * 3072 + 2048 + d0);
        vB = *(const u16x8*)(kb + (size_t)(2 * srow + 1) * 3072 + 2048 + d0);
      }

      f32x4 ST[4];
#pragma unroll
      for (int i = 0; i < 4; ++i) {
        bf16x8 ak0 = *(const bf16x8*)&Ks[(i * 16 + l16) * 72 + quad * 8];
        bf16x8 ak1 = *(const bf16x8*)&Ks[(i * 16 + l16) * 72 + 32 + quad * 8];
        f32x4 z = {};
        z = __builtin_amdgcn_mfma_f32_16x16x32_bf16(ak0, bq0, z, 0, 0, 0);
        ST[i] = __builtin_amdgcn_mfma_f32_16x16x32_bf16(ak1, bq1, z, 0, 0, 0);
      }

      bool dm = (kt == qt);
      float p[4][4];
      float mx = NEG_BIG;
#pragma unroll
      for (int i = 0; i < 4; ++i)
#pragma unroll
        for (int r = 0; r < 4; ++r) {
          float v = ST[i][r] * EXP2SC;
          int srel = i * 16 + quad * 4 + r;
          if (dm && srel > qrel) v = NEG_BIG;
          p[i][r] = v;
          mx = fmaxf(mx, v);
        }
      mx = fmaxf(mx, __shfl_xor(mx, 16));
      mx = fmaxf(mx, __shfl_xor(mx, 32));
      float mn = fmaxf(m_i, mx);
      float alpha = exp2f(m_i - mn);
      m_i = mn;
      float sum = 0.f;
#pragma unroll
      for (int i = 0; i < 4; ++i)
#pragma unroll
        for (int r = 0; r < 4; ++r) {
          float e = exp2f(p[i][r] - mn);
          p[i][r] = e;
          sum += e;
        }
      sum += __shfl_xor(sum, 16);
      sum += __shfl_xor(sum, 32);
      l_i = alpha * l_i + sum;

#pragma unroll
      for (int i = 0; i < 4; ++i) {
        uint2 pr;
        pr.x = pk2bf(p[i][0], p[i][1]);
        pr.y = pk2bf(p[i][2], p[i][3]);
        *(uint2*)(Pw + l16 * 72 + i * 16 + quad * 4) = pr;
      }

      float ar[4];
#pragma unroll
      for (int r = 0; r < 4; ++r)
        ar[r] = __shfl(alpha, (lane & 48) | (quad * 4 + r));
#pragma unroll
      for (int jd = 0; jd < 4; ++jd)
#pragma unroll
        for (int r = 0; r < 4; ++r) O[jd][r] *= ar[r];

#pragma unroll
      for (int ks = 0; ks < 2; ++ks) {
        bf16x8 ap = *(const bf16x8*)(Pw + l16 * 72 + ks * 32 + quad * 8);
#pragma unroll
        for (int jd = 0; jd < 4; ++jd) {
          union { unsigned int u[4]; bf16x8 v; } bv;
          int vbase = (jd * 16 + l16) * 35 + ks * 16 + quad * 4;
#pragma unroll
          for (int cc = 0; cc < 4; ++cc) bv.u[cc] = Vt[vbase + cc];
          O[jd] = __builtin_amdgcn_mfma_f32_16x16x32_bf16(ap, bv.v, O[jd], 0, 0, 0);
        }
      }
      __syncthreads();
    }

    float li[4];
#pragma unroll
    for (int r = 0; r < 4; ++r)
      li[r] = 1.f / __shfl(l_i, (lane & 48) | (quad * 4 + r));
#pragma unroll
    for (int jd = 0; jd < 4; ++jd)
#pragma unroll
      for (int r = 0; r < 4; ++r) {
        size_t row = (size_t)b * 2048 + q0 + w * 16 + quad * 4 + r;
        out[row * 1024 + h * 64 + jd * 16 + l16] = f2b(O[jd][r] * li[r]);
      }
  }
}

// ---------------------------------------------------------------------------
extern "C" void kernel_launch(void* const* d_in, const int* in_sizes, int n_in,
                              void* d_out, int out_size, void* d_ws, size_t ws_size,
                              hipStream_t stream) {
  (void)in_sizes; (void)n_in; (void)out_size;
  const void* x     = d_in[0];
  const void* ln1s  = d_in[2];
  const void* ln1b  = d_in[3];
  const void* ln2s  = d_in[4];
  const void* ln2b  = d_in[5];
  const void* w_qkv = d_in[6];
  const void* b_qkv = d_in[7];
  const void* w_ap  = d_in[8];
  const void* b_ap  = d_in[9];
  const void* w_fc  = d_in[10];
  const void* b_fc  = d_in[11];
  const void* w_mp  = d_in[12];
  const void* b_mp  = d_in[13];
  char* ws = (char*)d_ws;

  const int M = 4096, D = 1024, DFF = 4096, QKV3 = 3072;
  size_t off = 0;
  auto alloc = [&](size_t n) { char* p = ws + off; off += n; return p; };
  int* flag            = (int*)alloc(256);
  unsigned short* wT   = (unsigned short*)alloc((size_t)DFF * D * 2);   // 8 MiB
  unsigned short* hbuf = (unsigned short*)alloc((size_t)M * D * 2);     // 8 MiB (LN out / attn out)
  unsigned short* x1   = (unsigned short*)alloc((size_t)M * D * 2);     // 8 MiB
  char* region = alloc((size_t)M * DFF * 2);                            // 32 MiB
  unsigned short* qkvb = (unsigned short*)region;                       // [4096][3072] 24 MiB
  float* P0a = (float*)region;                                          // 16 MiB (after qkvb dead)
  float* P1a = (float*)(region + (size_t)M * D * 4);                    // 16 MiB
  unsigned short* fcb  = (unsigned short*)region;                       // [4096][4096] 32 MiB
  bool mlpSplit = ws_size >= off + (size_t)M * D * 8 + 1024;
  float* P0m = (float*)(ws + off);
  float* P1m = P0m + (size_t)M * D;

  dim3 blk(256);
  detect_k<<<dim3(1), dim3(64), 0, stream>>>((const unsigned short*)x, flag);
  // --- attention branch ---
  transpose_k<<<dim3(QKV3 / 64, D / 64), blk, 0, stream>>>(w_qkv, wT, D, QKV3, flag);
  ln_k<<<dim3(M), blk, 0, stream>>>(x, ln1s, ln1b, hbuf, flag, 1);
  gemm_bt<0><<<dim3(QKV3 / 128, M / 128), blk, 0, stream>>>(hbuf, wT, b_qkv, nullptr, qkvb, M, QKV3, D, flag, 0, 0);
  attn_k<<<dim3(16, 32), blk, 0, stream>>>(qkvb, hbuf);
  transpose_k<<<dim3(D / 64, D / 64), blk, 0, stream>>>(w_ap, wT, D, D, flag);
  gemm_pk<<<dim3(D / 128, M / 128, 2), blk, 0, stream>>>(hbuf, wT, P0a, M, D, D / 2, D);
  reduce2_k<<<dim3(M * D / 1024), blk, 0, stream>>>(P0a, P1a, b_ap, x, x1, D, flag, 1, 0);
  // --- MLP branch ---
  transpose_k<<<dim3(DFF / 64, D / 64), blk, 0, stream>>>(w_fc, wT, D, DFF, flag);
  ln_k<<<dim3(M), blk, 0, stream>>>(x1, ln2s, ln2b, hbuf, flag, 0);
  gemm_bt<1><<<dim3(DFF / 128, M / 128), blk, 0, stream>>>(hbuf, wT, b_fc, nullptr, fcb, M, DFF, D, flag, 0, 0);
  transpose_k<<<dim3(D / 64, DFF / 64), blk, 0, stream>>>(w_mp, wT, DFF, D, flag);
  if (mlpSplit) {
    gemm_pk<<<dim3(D / 128, M / 128, 2), blk, 0, stream>>>(fcb, wT, P0m, M, D, DFF / 2, DFF);
    reduce2_k<<<dim3(M * D / 1024), blk, 0, stream>>>(P0m, P1m, b_mp, x1, d_out, D, flag, 0, 1);
  } else {
    gemm_bt<2><<<dim3(D / 128, M / 128), blk, 0, stream>>>(fcb, wT, b_mp, x1, d_out, M, D, DFF, flag, 0, 1);
  }
}

// Round 9
// 408.008 us; speedup vs baseline: 1.1277x; 1.0139x over previous
//
#include <hip/hip_runtime.h>
#include <hip/hip_bf16.h>
#include <stdint.h>

// ---------------------------------------------------------------------------
// GPT-2 block, runtime dtype-adaptive (fp32 or bf16 external), bf16 internal,
// fp32 accumulate. MI355X / gfx950.
// R9: gemm_bt reverted to R7 (BK=64 glds, best measured 75us); gemm_pk keeps
// R8 single-barrier dbuf (helped ~17us); attn-proj reduce fused with LN2.
// ---------------------------------------------------------------------------

typedef __attribute__((ext_vector_type(8))) short bf16x8;
typedef __attribute__((ext_vector_type(8))) unsigned short u16x8;
typedef __attribute__((ext_vector_type(4))) float f32x4;

#define NEG_BIG -30000.0f
#define EXP2SC 0.18033688011112042f   // 0.125 * log2(e)

__device__ __forceinline__ float b2f(unsigned short u) {
  union { unsigned int i; float f; } c; c.i = ((unsigned int)u) << 16; return c.f;
}
__device__ __forceinline__ unsigned short f2b(float f) {
  union { float f; unsigned int u; } c; c.f = f;
  unsigned int r = c.u + 0x7fffu + ((c.u >> 16) & 1u);   // RNE
  return (unsigned short)(r >> 16);
}
__device__ __forceinline__ unsigned int pk2bf(float a, float b) {
  float2 f; f.x = a; f.y = b;
  union { __hip_bfloat162 h; unsigned int u; } c;
  c.h = __float22bfloat162_rn(f);      // v_cvt_pk_bf16_f32
  return c.u;
}
__device__ __forceinline__ float ldx(const void* p, size_t i, int f32) {
  return f32 ? ((const float*)p)[i] : b2f(((const unsigned short*)p)[i]);
}
__device__ __forceinline__ void gld_lds16(const void* g, void* l) {
  __builtin_amdgcn_global_load_lds(
      (__attribute__((address_space(1))) void*)(void*)g,
      (__attribute__((address_space(3))) void*)l, 16, 0, 0);
}

// ---------------------------------------------------------------------------
__global__ void detect_k(const unsigned short* __restrict__ x, int* __restrict__ flag) {
  int lane = threadIdx.x;
  int cnt = 0;
#pragma unroll
  for (int j = 0; j < 4; ++j) {
    unsigned e = (x[lane * 4 + j] >> 7) & 0xFF;
    if (e >= 100 && e <= 145) cnt++;
  }
#pragma unroll
  for (int off = 32; off; off >>= 1) cnt += __shfl_down(cnt, off);
  if (lane == 0) *flag = (cnt < 220) ? 1 : 0;
}

// ---------------------------------------------------------------------------
// 64x64 tile transpose, adaptive input, bf16 out: out[n*K+k] = in[k*N+n]
// ---------------------------------------------------------------------------
__global__ __launch_bounds__(256) void transpose_k(
    const void* __restrict__ in, unsigned short* __restrict__ out,
    int K, int N, const int* __restrict__ flag) {
  int fm = *flag;
  __shared__ unsigned short tile[64][72];
  int n0 = blockIdx.x * 64, k0 = blockIdx.y * 64;
  int t = threadIdx.x;
  int r = t >> 3, c0 = (t & 7) * 8;
  if (fm) {
    const float* inf = (const float*)in;
#pragma unroll
    for (int p = 0; p < 2; ++p) {
      int k = r + p * 32;
      float4 v0 = *(const float4*)(inf + (size_t)(k0 + k) * N + n0 + c0);
      float4 v1 = *(const float4*)(inf + (size_t)(k0 + k) * N + n0 + c0 + 4);
      tile[k][c0 + 0] = f2b(v0.x); tile[k][c0 + 1] = f2b(v0.y);
      tile[k][c0 + 2] = f2b(v0.z); tile[k][c0 + 3] = f2b(v0.w);
      tile[k][c0 + 4] = f2b(v1.x); tile[k][c0 + 5] = f2b(v1.y);
      tile[k][c0 + 6] = f2b(v1.z); tile[k][c0 + 7] = f2b(v1.w);
    }
  } else {
    const unsigned short* inu = (const unsigned short*)in;
#pragma unroll
    for (int p = 0; p < 2; ++p) {
      int k = r + p * 32;
      u16x8 v = *(const u16x8*)(inu + (size_t)(k0 + k) * N + n0 + c0);
      *(u16x8*)&tile[k][c0] = v;
    }
  }
  __syncthreads();
#pragma unroll
  for (int p = 0; p < 2; ++p) {
    int n = r + p * 32;
    u16x8 v;
#pragma unroll
    for (int j = 0; j < 8; ++j) v[j] = tile[c0 + j][n];
    *(u16x8*)(out + (size_t)(n0 + n) * K + k0 + c0) = v;
  }
}

// ---------------------------------------------------------------------------
// LayerNorm D=1024
// ---------------------------------------------------------------------------
__global__ __launch_bounds__(256) void ln_k(
    const void* __restrict__ x, const void* __restrict__ sc,
    const void* __restrict__ bs, unsigned short* __restrict__ out,
    const int* __restrict__ flag, int xAdap) {
  int fm = *flag;
  int fx = xAdap ? fm : 0;
  int row = blockIdx.x, t = threadIdx.x;
  float f0, f1, f2, f3;
  if (fx) {
    float4 xv = ((const float4*)x)[(size_t)row * 256 + t];
    f0 = xv.x; f1 = xv.y; f2 = xv.z; f3 = xv.w;
  } else {
    ushort4 xv = ((const ushort4*)x)[(size_t)row * 256 + t];
    f0 = b2f(xv.x); f1 = b2f(xv.y); f2 = b2f(xv.z); f3 = b2f(xv.w);
  }
  float s = f0 + f1 + f2 + f3;
  float q = f0 * f0 + f1 * f1 + f2 * f2 + f3 * f3;
#pragma unroll
  for (int off = 32; off; off >>= 1) {
    s += __shfl_down(s, off);
    q += __shfl_down(q, off);
  }
  __shared__ float red[8];
  int w = t >> 6, lane = t & 63;
  if (lane == 0) { red[w] = s; red[w + 4] = q; }
  __syncthreads();
  float S = red[0] + red[1] + red[2] + red[3];
  float Q = red[4] + red[5] + red[6] + red[7];
  float mean = S * (1.f / 1024.f);
  float var = Q * (1.f / 1024.f) - mean * mean;
  float rstd = rsqrtf(var + 1e-5f);
  int c = t * 4;
  ushort4 o;
  o.x = f2b((f0 - mean) * rstd * ldx(sc, c, fm)     + ldx(bs, c, fm));
  o.y = f2b((f1 - mean) * rstd * ldx(sc, c + 1, fm) + ldx(bs, c + 1, fm));
  o.z = f2b((f2 - mean) * rstd * ldx(sc, c + 2, fm) + ldx(bs, c + 2, fm));
  o.w = f2b((f3 - mean) * rstd * ldx(sc, c + 3, fm) + ldx(bs, c + 3, fm));
  ((ushort4*)(out + (size_t)row * 1024))[t] = o;
}

// ---------------------------------------------------------------------------
// GEMM (R7 form): C[M,N] = A[M,K]*Bt[N,K]^T + bias; EPI: 0=none 1=gelu 2=+res
// 128x128 tile, BK=64 via two 32-col half-buffers per operand, glds width=16.
// ---------------------------------------------------------------------------
template <int EPI>
__global__ __launch_bounds__(256) void gemm_bt(
    const unsigned short* __restrict__ A, const unsigned short* __restrict__ Bt,
    const void* __restrict__ bias, const void* __restrict__ res,
    void* __restrict__ C, int M, int N, int K,
    const int* __restrict__ flag, int resAdap, int outAdap) {
  int fm = *flag;
  int fr = resAdap ? fm : 0;
  int fo = outAdap ? fm : 0;
  __shared__ unsigned short As[2][128 * 32];
  __shared__ unsigned short Bs[2][128 * 32];
  int t = threadIdx.x;
  int bn = blockIdx.x * 128, bm = blockIdx.y * 128;
  int w = t >> 6, lane = t & 63, quad = lane >> 4, l16 = lane & 15;
  int wm = (w >> 1) * 64, wn = (w & 1) * 64;
  f32x4 acc[4][4] = {};

  int c1 = t, c2 = t + 256;
  int r1 = c1 >> 2, e1 = (c1 & 3) * 8;
  int r2 = c2 >> 2, e2 = (c2 & 3) * 8;
  const unsigned short* a1 = A + (size_t)(bm + r1) * K + e1;
  const unsigned short* a2 = A + (size_t)(bm + r2) * K + e2;
  const unsigned short* b1 = Bt + (size_t)(bn + r1) * K + e1;
  const unsigned short* b2 = Bt + (size_t)(bn + r2) * K + e2;

  for (int k0 = 0; k0 < K; k0 += 64) {
    gld_lds16(a1 + k0,      As[0] + c1 * 8);
    gld_lds16(a2 + k0,      As[0] + c2 * 8);
    gld_lds16(a1 + k0 + 32, As[1] + c1 * 8);
    gld_lds16(a2 + k0 + 32, As[1] + c2 * 8);
    gld_lds16(b1 + k0,      Bs[0] + c1 * 8);
    gld_lds16(b2 + k0,      Bs[0] + c2 * 8);
    gld_lds16(b1 + k0 + 32, Bs[1] + c1 * 8);
    gld_lds16(b2 + k0 + 32, Bs[1] + c2 * 8);
    __syncthreads();
#pragma unroll
    for (int h = 0; h < 2; ++h) {
      bf16x8 af[4], bfr[4];
#pragma unroll
      for (int i = 0; i < 4; ++i)
        af[i] = *(const bf16x8*)&As[h][(wm + i * 16 + l16) * 32 + quad * 8];
#pragma unroll
      for (int j = 0; j < 4; ++j)
        bfr[j] = *(const bf16x8*)&Bs[h][(wn + j * 16 + l16) * 32 + quad * 8];
#pragma unroll
      for (int i = 0; i < 4; ++i)
#pragma unroll
        for (int j = 0; j < 4; ++j)
          acc[i][j] = __builtin_amdgcn_mfma_f32_16x16x32_bf16(af[i], bfr[j], acc[i][j], 0, 0, 0);
    }
    __syncthreads();
  }

#pragma unroll
  for (int j = 0; j < 4; ++j) {
    int col = bn + wn + j * 16 + l16;
    float bb = ldx(bias, col, fm);
#pragma unroll
    for (int i = 0; i < 4; ++i) {
      int row0 = bm + wm + i * 16 + quad * 4;
#pragma unroll
      for (int r = 0; r < 4; ++r) {
        float v = acc[i][j][r] + bb;
        if (EPI == 1) {
          float u = 0.7978845608f * (v + 0.044715f * v * v * v);
          float e = __expf(2.f * u);          // tanh(u) = 1 - 2/(e^{2u}+1)
          float th = 1.f - 2.f / (e + 1.f);
          v = 0.5f * v * (1.f + th);
        } else if (EPI == 2) {
          v += ldx(res, (size_t)(row0 + r) * N + col, fr);
        }
        size_t idx = (size_t)(row0 + r) * N + col;
        if (fo) ((float*)C)[idx] = v;
        else    ((unsigned short*)C)[idx] = f2b(v);
      }
    }
  }
}

// ---------------------------------------------------------------------------
// Split-K GEMM (R8 form): P[z][M,N] = A[:, z*Kh:(z+1)*Kh] * Bt^T (fp32)
// BK=32, dbuf LDS, reg-prefetch, single barrier per K-step.
// ---------------------------------------------------------------------------
__global__ __launch_bounds__(256) void gemm_pk(
    const unsigned short* __restrict__ A, const unsigned short* __restrict__ Bt,
    float* __restrict__ P, int M, int N, int Kh, int Kfull) {
  __shared__ unsigned short As[2][128 * 32];
  __shared__ unsigned short Bs[2][128 * 32];
  int t = threadIdx.x;
  int bn = blockIdx.x * 128, bm = blockIdx.y * 128;
  int koff = blockIdx.z * Kh;
  float* Pz = P + (size_t)blockIdx.z * M * N;
  int w = t >> 6, lane = t & 63, quad = lane >> 4, l16 = lane & 15;
  int wm = (w >> 1) * 64, wn = (w & 1) * 64;
  f32x4 acc[4][4] = {};

  int c1 = t, c2 = t + 256;
  int r1 = c1 >> 2, e1 = (c1 & 3) * 8;
  int r2 = c2 >> 2, e2 = (c2 & 3) * 8;
  const unsigned short* a1 = A + (size_t)(bm + r1) * Kfull + koff + e1;
  const unsigned short* a2 = A + (size_t)(bm + r2) * Kfull + koff + e2;
  const unsigned short* b1 = Bt + (size_t)(bn + r1) * Kfull + koff + e1;
  const unsigned short* b2 = Bt + (size_t)(bn + r2) * Kfull + koff + e2;

  u16x8 va1 = *(const u16x8*)a1;
  u16x8 va2 = *(const u16x8*)a2;
  u16x8 vb1 = *(const u16x8*)b1;
  u16x8 vb2 = *(const u16x8*)b2;

  int nIter = Kh >> 5;
  for (int it = 0; it < nIter; ++it) {
    unsigned short* Ab = As[it & 1];
    unsigned short* Bb = Bs[it & 1];
    *(u16x8*)(Ab + c1 * 8) = va1;
    *(u16x8*)(Ab + c2 * 8) = va2;
    *(u16x8*)(Bb + c1 * 8) = vb1;
    *(u16x8*)(Bb + c2 * 8) = vb2;
    __syncthreads();
    if (it + 1 < nIter) {
      int k0 = (it + 1) << 5;
      va1 = *(const u16x8*)(a1 + k0);
      va2 = *(const u16x8*)(a2 + k0);
      vb1 = *(const u16x8*)(b1 + k0);
      vb2 = *(const u16x8*)(b2 + k0);
    }
    bf16x8 af[4], bfr[4];
#pragma unroll
    for (int i = 0; i < 4; ++i)
      af[i] = *(const bf16x8*)&Ab[(wm + i * 16 + l16) * 32 + quad * 8];
#pragma unroll
    for (int j = 0; j < 4; ++j)
      bfr[j] = *(const bf16x8*)&Bb[(wn + j * 16 + l16) * 32 + quad * 8];
#pragma unroll
    for (int i = 0; i < 4; ++i)
#pragma unroll
      for (int j = 0; j < 4; ++j)
        acc[i][j] = __builtin_amdgcn_mfma_f32_16x16x32_bf16(af[i], bfr[j], acc[i][j], 0, 0, 0);
  }

#pragma unroll
  for (int j = 0; j < 4; ++j) {
    int col = bn + wn + j * 16 + l16;
#pragma unroll
    for (int i = 0; i < 4; ++i) {
      int row0 = bm + wm + i * 16 + quad * 4;
#pragma unroll
      for (int r = 0; r < 4; ++r)
        Pz[(size_t)(row0 + r) * N + col] = acc[i][j][r];
    }
  }
}

// ---------------------------------------------------------------------------
// reduce: out = P0 + P1 + bias (+ res), N power of two (final mlp output)
// ---------------------------------------------------------------------------
__global__ __launch_bounds__(256) void reduce2_k(
    const float* __restrict__ P0, const float* __restrict__ P1,
    const void* __restrict__ bias, const void* __restrict__ res,
    void* __restrict__ out, int N,
    const int* __restrict__ flag, int resAdap, int outAdap) {
  int fm = *flag;
  int fr = resAdap ? fm : 0;
  int fo = outAdap ? fm : 0;
  size_t idx = ((size_t)blockIdx.x * 256 + threadIdx.x) * 4;
  float4 p0 = *(const float4*)(P0 + idx);
  float4 p1 = *(const float4*)(P1 + idx);
  int col = (int)(idx & (size_t)(N - 1));
  float v0 = p0.x + p1.x + ldx(bias, col, fm)     + ldx(res, idx, fr);
  float v1 = p0.y + p1.y + ldx(bias, col + 1, fm) + ldx(res, idx + 1, fr);
  float v2 = p0.z + p1.z + ldx(bias, col + 2, fm) + ldx(res, idx + 2, fr);
  float v3 = p0.w + p1.w + ldx(bias, col + 3, fm) + ldx(res, idx + 3, fr);
  if (fo) {
    float4 o; o.x = v0; o.y = v1; o.z = v2; o.w = v3;
    *(float4*)((float*)out + idx) = o;
  } else {
    ushort4 o; o.x = f2b(v0); o.y = f2b(v1); o.z = f2b(v2); o.w = f2b(v3);
    *(ushort4*)((unsigned short*)out + idx) = o;
  }
}

// ---------------------------------------------------------------------------
// fused: x1 = P0 + P1 + bias + x (residual, adaptive); then LN(x1) -> h
// One block per row (D=1024). Writes x1 (bf16) and h (bf16).
// ---------------------------------------------------------------------------
__global__ __launch_bounds__(256) void reduce2ln_k(
    const float* __restrict__ P0, const float* __restrict__ P1,
    const void* __restrict__ bias, const void* __restrict__ resx,
    unsigned short* __restrict__ x1, unsigned short* __restrict__ hout,
    const void* __restrict__ sc, const void* __restrict__ bs,
    const int* __restrict__ flag) {
  int fm = *flag;
  int row = blockIdx.x, t = threadIdx.x;
  size_t base = (size_t)row * 1024 + t * 4;
  float4 p0 = *(const float4*)(P0 + base);
  float4 p1 = *(const float4*)(P1 + base);
  int c = t * 4;
  float f0 = p0.x + p1.x + ldx(bias, c, fm)     + ldx(resx, base, fm);
  float f1 = p0.y + p1.y + ldx(bias, c + 1, fm) + ldx(resx, base + 1, fm);
  float f2 = p0.z + p1.z + ldx(bias, c + 2, fm) + ldx(resx, base + 2, fm);
  float f3 = p0.w + p1.w + ldx(bias, c + 3, fm) + ldx(resx, base + 3, fm);
  ushort4 xo;
  xo.x = f2b(f0); xo.y = f2b(f1); xo.z = f2b(f2); xo.w = f2b(f3);
  ((ushort4*)(x1 + (size_t)row * 1024))[t] = xo;

  float s = f0 + f1 + f2 + f3;
  float q = f0 * f0 + f1 * f1 + f2 * f2 + f3 * f3;
#pragma unroll
  for (int off = 32; off; off >>= 1) {
    s += __shfl_down(s, off);
    q += __shfl_down(q, off);
  }
  __shared__ float red[8];
  int w = t >> 6, lane = t & 63;
  if (lane == 0) { red[w] = s; red[w + 4] = q; }
  __syncthreads();
  float S = red[0] + red[1] + red[2] + red[3];
  float Q = red[4] + red[5] + red[6] + red[7];
  float mean = S * (1.f / 1024.f);
  float var = Q * (1.f / 1024.f) - mean * mean;
  float rstd = rsqrtf(var + 1e-5f);
  ushort4 o;
  o.x = f2b((f0 - mean) * rstd * ldx(sc, c, fm)     + ldx(bs, c, fm));
  o.y = f2b((f1 - mean) * rstd * ldx(sc, c + 1, fm) + ldx(bs, c + 1, fm));
  o.z = f2b((f2 - mean) * rstd * ldx(sc, c + 2, fm) + ldx(bs, c + 2, fm));
  o.w = f2b((f3 - mean) * rstd * ldx(sc, c + 3, fm) + ldx(bs, c + 3, fm));
  ((ushort4*)(hout + (size_t)row * 1024))[t] = o;
}

// ---------------------------------------------------------------------------
// Flash attention, causal, S^T formulation, paired q-tiles (pi, 31-pi),
// register prefetch of next K/V tile. (R7, unchanged)
// ---------------------------------------------------------------------------
__global__ __launch_bounds__(256) void attn_k(
    const unsigned short* __restrict__ qkv, unsigned short* __restrict__ out) {
  __shared__ unsigned short Ks[64 * 72];
  __shared__ unsigned int   Vt[64 * 35];
  __shared__ unsigned short Ps[4 * 16 * 72];
  int t = threadIdx.x, w = t >> 6, lane = t & 63, quad = lane >> 4, l16 = lane & 15;
  int pi = blockIdx.x, bh = blockIdx.y, b = bh >> 4, h = bh & 15;
  const unsigned short* base = qkv + (size_t)b * 2048 * 3072 + h * 64;
  unsigned short* Pw = Ps + w * 16 * 72;
  int srow = t >> 3, d0 = (t & 7) * 8;

#pragma unroll 1
  for (int half = 0; half < 2; ++half) {
    int qt = half ? (31 - pi) : pi;
    int q0 = qt * 64;
    int qrel = w * 16 + l16;
    const unsigned short* qp = base + (size_t)(q0 + qrel) * 3072;
    bf16x8 bq0 = *(const bf16x8*)(qp + quad * 8);
    bf16x8 bq1 = *(const bf16x8*)(qp + 32 + quad * 8);
    float m_i = NEG_BIG, l_i = 0.f;
    f32x4 O[4] = {};

    u16x8 kA, kB, vA, vB;
    {
      const unsigned short* kb = base;
      kA = *(const u16x8*)(kb + (size_t)srow * 3072 + 1024 + d0);
      kB = *(const u16x8*)(kb + (size_t)(srow + 32) * 3072 + 1024 + d0);
      vA = *(const u16x8*)(kb + (size_t)(2 * srow) * 3072 + 2048 + d0);
      vB = *(const u16x8*)(kb + (size_t)(2 * srow + 1) * 3072 + 2048 + d0);
    }

#pragma unroll 1
    for (int kt = 0; kt <= qt; ++kt) {
      *(u16x8*)&Ks[srow * 72 + d0] = kA;
      *(u16x8*)&Ks[(srow + 32) * 72 + d0] = kB;
#pragma unroll
      for (int j = 0; j < 8; ++j)
        Vt[(d0 + j) * 35 + srow] = (unsigned int)vA[j] | ((unsigned int)vB[j] << 16);
      __syncthreads();

      if (kt < qt) {
        const unsigned short* kb = base + (size_t)((kt + 1) * 64) * 3072;
        kA = *(const u16x8*)(kb + (size_t)srow * 3072 + 1024 + d0);
        kB = *(const u16x8*)(kb + (size_t)(srow + 32) * 3072 + 1024 + d0);
        vA = *(const u16x8*)(kb + (size_t)(2 * srow) * 3072 + 2048 + d0);
        vB = *(const u16x8*)(kb + (size_t)(2 * srow + 1) * 3072 + 2048 + d0);
      }

      f32x4 ST[4];
#pragma unroll
      for (int i = 0; i < 4; ++i) {
        bf16x8 ak0 = *(const bf16x8*)&Ks[(i * 16 + l16) * 72 + quad * 8];
        bf16x8 ak1 = *(const bf16x8*)&Ks[(i * 16 + l16) * 72 + 32 + quad * 8];
        f32x4 z = {};
        z = __builtin_amdgcn_mfma_f32_16x16x32_bf16(ak0, bq0, z, 0, 0, 0);
        ST[i] = __builtin_amdgcn_mfma_f32_16x16x32_bf16(ak1, bq1, z, 0, 0, 0);
      }

      bool dm = (kt == qt);
      float p[4][4];
      float mx = NEG_BIG;
#pragma unroll
      for (int i = 0; i < 4; ++i)
#pragma unroll
        for (int r = 0; r < 4; ++r) {
          float v = ST[i][r] * EXP2SC;
          int srel = i * 16 + quad * 4 + r;
          if (dm && srel > qrel) v = NEG_BIG;
          p[i][r] = v;
          mx = fmaxf(mx, v);
        }
      mx = fmaxf(mx, __shfl_xor(mx, 16));
      mx = fmaxf(mx, __shfl_xor(mx, 32));
      float mn = fmaxf(m_i, mx);
      float alpha = exp2f(m_i - mn);
      m_i = mn;
      float sum = 0.f;
#pragma unroll
      for (int i = 0; i < 4; ++i)
#pragma unroll
        for (int r = 0; r < 4; ++r) {
          float e = exp2f(p[i][r] - mn);
          p[i][r] = e;
          sum += e;
        }
      sum += __shfl_xor(sum, 16);
      sum += __shfl_xor(sum, 32);
      l_i = alpha * l_i + sum;

#pragma unroll
      for (int i = 0; i < 4; ++i) {
        uint2 pr;
        pr.x = pk2bf(p[i][0], p[i][1]);
        pr.y = pk2bf(p[i][2], p[i][3]);
        *(uint2*)(Pw + l16 * 72 + i * 16 + quad * 4) = pr;
      }

      float ar[4];
#pragma unroll
      for (int r = 0; r < 4; ++r)
        ar[r] = __shfl(alpha, (lane & 48) | (quad * 4 + r));
#pragma unroll
      for (int jd = 0; jd < 4; ++jd)
#pragma unroll
        for (int r = 0; r < 4; ++r) O[jd][r] *= ar[r];

#pragma unroll
      for (int ks = 0; ks < 2; ++ks) {
        bf16x8 ap = *(const bf16x8*)(Pw + l16 * 72 + ks * 32 + quad * 8);
#pragma unroll
        for (int jd = 0; jd < 4; ++jd) {
          union { unsigned int u[4]; bf16x8 v; } bv;
          int vbase = (jd * 16 + l16) * 35 + ks * 16 + quad * 4;
#pragma unroll
          for (int cc = 0; cc < 4; ++cc) bv.u[cc] = Vt[vbase + cc];
          O[jd] = __builtin_amdgcn_mfma_f32_16x16x32_bf16(ap, bv.v, O[jd], 0, 0, 0);
        }
      }
      __syncthreads();
    }

    float li[4];
#pragma unroll
    for (int r = 0; r < 4; ++r)
      li[r] = 1.f / __shfl(l_i, (lane & 48) | (quad * 4 + r));
#pragma unroll
    for (int jd = 0; jd < 4; ++jd)
#pragma unroll
      for (int r = 0; r < 4; ++r) {
        size_t row = (size_t)b * 2048 + q0 + w * 16 + quad * 4 + r;
        out[row * 1024 + h * 64 + jd * 16 + l16] = f2b(O[jd][r] * li[r]);
      }
  }
}

// ---------------------------------------------------------------------------
extern "C" void kernel_launch(void* const* d_in, const int* in_sizes, int n_in,
                              void* d_out, int out_size, void* d_ws, size_t ws_size,
                              hipStream_t stream) {
  (void)in_sizes; (void)n_in; (void)out_size;
  const void* x     = d_in[0];
  const void* ln1s  = d_in[2];
  const void* ln1b  = d_in[3];
  const void* ln2s  = d_in[4];
  const void* ln2b  = d_in[5];
  const void* w_qkv = d_in[6];
  const void* b_qkv = d_in[7];
  const void* w_ap  = d_in[8];
  const void* b_ap  = d_in[9];
  const void* w_fc  = d_in[10];
  const void* b_fc  = d_in[11];
  const void* w_mp  = d_in[12];
  const void* b_mp  = d_in[13];
  char* ws = (char*)d_ws;

  const int M = 4096, D = 1024, DFF = 4096, QKV3 = 3072;
  size_t off = 0;
  auto alloc = [&](size_t n) { char* p = ws + off; off += n; return p; };
  int* flag            = (int*)alloc(256);
  unsigned short* wT   = (unsigned short*)alloc((size_t)DFF * D * 2);   // 8 MiB
  unsigned short* hbuf = (unsigned short*)alloc((size_t)M * D * 2);     // 8 MiB (LN out / attn out)
  unsigned short* x1   = (unsigned short*)alloc((size_t)M * D * 2);     // 8 MiB
  char* region = alloc((size_t)M * DFF * 2);                            // 32 MiB
  unsigned short* qkvb = (unsigned short*)region;                       // [4096][3072] 24 MiB
  float* P0a = (float*)region;                                          // 16 MiB (after qkvb dead)
  float* P1a = (float*)(region + (size_t)M * D * 4);                    // 16 MiB
  unsigned short* fcb  = (unsigned short*)region;                       // [4096][4096] 32 MiB
  bool mlpSplit = ws_size >= off + (size_t)M * D * 8 + 1024;
  float* P0m = (float*)(ws + off);
  float* P1m = P0m + (size_t)M * D;

  dim3 blk(256);
  detect_k<<<dim3(1), dim3(64), 0, stream>>>((const unsigned short*)x, flag);
  // --- attention branch ---
  transpose_k<<<dim3(QKV3 / 64, D / 64), blk, 0, stream>>>(w_qkv, wT, D, QKV3, flag);
  ln_k<<<dim3(M), blk, 0, stream>>>(x, ln1s, ln1b, hbuf, flag, 1);
  gemm_bt<0><<<dim3(QKV3 / 128, M / 128), blk, 0, stream>>>(hbuf, wT, b_qkv, nullptr, qkvb, M, QKV3, D, flag, 0, 0);
  attn_k<<<dim3(16, 32), blk, 0, stream>>>(qkvb, hbuf);
  transpose_k<<<dim3(D / 64, D / 64), blk, 0, stream>>>(w_ap, wT, D, D, flag);
  gemm_pk<<<dim3(D / 128, M / 128, 2), blk, 0, stream>>>(hbuf, wT, P0a, M, D, D / 2, D);
  // fused: x1 = P0a+P1a+b_ap+x ; hbuf = LN2(x1)
  reduce2ln_k<<<dim3(M), blk, 0, stream>>>(P0a, P1a, b_ap, x, x1, hbuf, ln2s, ln2b, flag);
  // --- MLP branch ---
  transpose_k<<<dim3(DFF / 64, D / 64), blk, 0, stream>>>(w_fc, wT, D, DFF, flag);
  gemm_bt<1><<<dim3(DFF / 128, M / 128), blk, 0, stream>>>(hbuf, wT, b_fc, nullptr, fcb, M, DFF, D, flag, 0, 0);
  transpose_k<<<dim3(D / 64, DFF / 64), blk, 0, stream>>>(w_mp, wT, DFF, D, flag);
  if (mlpSplit) {
    gemm_pk<<<dim3(D / 128, M / 128, 2), blk, 0, stream>>>(fcb, wT, P0m, M, D, DFF / 2, DFF);
    reduce2_k<<<dim3(M * D / 1024), blk, 0, stream>>>(P0m, P1m, b_mp, x1, d_out, D, flag, 0, 1);
  } else {
    gemm_bt<2><<<dim3(D / 128, M / 128), blk, 0, stream>>>(fcb, wT, b_mp, x1, d_out, M, D, DFF, flag, 0, 1);
  }
}